// Round 1
// baseline (2679.688 us; speedup 1.0000x reference)
//
#include <hip/hip_runtime.h>

#define BATCH 16
#define NPTS  2048
#define NMAT  32   // 16 batches x 2 preds
#define ITERS 20

__device__ __forceinline__ float fexp2(float x){ return __builtin_amdgcn_exp2f(x); }
__device__ __forceinline__ float flog2(float x){ return __builtin_amdgcn_logf(x); }
__device__ __forceinline__ float fsqrt_(float x){ return __builtin_amdgcn_sqrtf(x); }

// K = log2(e)/EPS, EPS = 0.05.  Potentials stored pre-scaled: F = f*K, G = g*K.
// f-update becomes: F_i = -11 - M_i - log2(S_i),  y_ij = G_j - K*C_ij,
// M_i = max_j y_ij, S_i = sum_j 2^(y_ij - M_i).   (-11 = log2(1/2048))
constexpr float KSCALE = 28.853900817779268f;

__global__ void __launch_bounds__(256) pack_kernel(
    const float* __restrict__ gt, const float* __restrict__ p0, const float* __restrict__ p1,
    float4* __restrict__ P4, float4* __restrict__ G4,
    float* __restrict__ cost, float* __restrict__ chamf)
{
  int idx = blockIdx.x * 256 + threadIdx.x;
  if (idx < NMAT * NPTS) {
    int m = idx >> 11, i = idx & (NPTS - 1);
    int b = m >> 1;
    const float* s = (m & 1) ? p1 : p0;
    float x = s[(b * NPTS + i) * 3 + 0];
    float y = s[(b * NPTS + i) * 3 + 1];
    float z = s[(b * NPTS + i) * 3 + 2];
    P4[idx] = make_float4(x, y, z, x * x + y * y + z * z);
  } else if (idx < NMAT * NPTS + BATCH * NPTS) {
    int k = idx - NMAT * NPTS;
    float x = gt[k * 3 + 0], y = gt[k * 3 + 1], z = gt[k * 3 + 2];
    G4[k] = make_float4(x, y, z, x * x + y * y + z * z);
  } else if (idx < NMAT * NPTS + BATCH * NPTS + NMAT) {
    cost[idx - NMAT * NPTS - BATCH * NPTS] = 0.f;
  } else if (idx == NMAT * NPTS + BATCH * NPTS + NMAT) {
    chamf[0] = 0.f;
  }
}

// One Sinkhorn half-update over all 32 matrices.
// GSIDE=0: lanes = pred rows, loop over gt cols (f-update, writes F).
// GSIDE=1: lanes = gt cols, loop over pred rows (g-update, writes Gp).
// ZPOT: potential being summed over is identically zero (very first f-update).
// CHAM: also accumulate chamfer (min of squared dist along the loop axis).
template<int CHAM, int ZPOT, int GSIDE>
__global__ void __launch_bounds__(256) sink_kernel(
    const float4* __restrict__ P4, const float4* __restrict__ G4,
    const float* __restrict__ pot_in, float* __restrict__ pot_out,
    float* __restrict__ chamf)
{
  const int bx   = blockIdx.x;
  const int m    = bx >> 5;        // 32 row-blocks per matrix
  const int rb   = bx & 31;
  const int b    = m >> 1;
  const int lane = threadIdx.x & 63;
  const int wave = __builtin_amdgcn_readfirstlane(threadIdx.x >> 6);
  const int row  = rb * 64 + lane;

  const float4* lanePts = GSIDE ? (G4 + b * NPTS) : (P4 + m * NPTS);
  const float4* loopPts = GSIDE ? (P4 + m * NPTS) : (G4 + b * NPTS);
  const float*  pin     = pot_in + m * NPTS;

  const float4 p = lanePts[row];
  float mmax = -1e30f, s = 0.f, dmin = 1e30f;
  const int j0 = wave * (NPTS / 4);

  for (int jc = 0; jc < NPTS / 4; jc += 8) {
    float t[8];
#pragma unroll
    for (int u = 0; u < 8; ++u) {
      const int j = j0 + jc + u;
      const float4 g = loopPts[j];
      float dot = p.x * g.x + p.y * g.y + p.z * g.z;
      float d = fmaxf(fmaf(-2.f, dot, p.w + g.w), 0.f);
      if (CHAM) dmin = fminf(dmin, d);
      const float C = fsqrt_(d + 1e-12f);
      t[u] = ZPOT ? (-KSCALE * C) : fmaf(-KSCALE, C, pin[j]);
    }
    float cm = fmaxf(fmaxf(fmaxf(t[0], t[1]), fmaxf(t[2], t[3])),
                     fmaxf(fmaxf(t[4], t[5]), fmaxf(t[6], t[7])));
    const float nm = fmaxf(mmax, cm);
    s *= fexp2(mmax - nm);
#pragma unroll
    for (int u = 0; u < 8; ++u) s += fexp2(t[u] - nm);
    mmax = nm;
  }

  // combine the 4 column-split waves (log-domain merge), then write.
  __shared__ float sm[4][64], ss[4][64], sd[4][64];
  sm[wave][lane] = mmax;
  ss[wave][lane] = s;
  if (CHAM) sd[wave][lane] = dmin;
  __syncthreads();
  if (wave == 0) {
    float M = fmaxf(fmaxf(sm[0][lane], sm[1][lane]), fmaxf(sm[2][lane], sm[3][lane]));
    float S = ss[0][lane] * fexp2(sm[0][lane] - M)
            + ss[1][lane] * fexp2(sm[1][lane] - M)
            + ss[2][lane] * fexp2(sm[2][lane] - M)
            + ss[3][lane] * fexp2(sm[3][lane] - M);
    pot_out[m * NPTS + row] = -11.0f - M - flog2(S);
    if (CHAM) {
      float dm = fminf(fminf(sd[0][lane], sd[1][lane]), fminf(sd[2][lane], sd[3][lane]));
#pragma unroll
      for (int o = 32; o; o >>= 1) dm += __shfl_xor(dm, o);
      if (lane == 0) atomicAdd(chamf, dm);
    }
  }
}

// cost_m = sum_ij 2^(F_i + G_j - K*C_ij) * C_ij
__global__ void __launch_bounds__(256) cost_kernel(
    const float4* __restrict__ P4, const float4* __restrict__ G4,
    const float* __restrict__ F, const float* __restrict__ Gp,
    float* __restrict__ cost)
{
  const int bx   = blockIdx.x;
  const int m    = bx >> 5;
  const int rb   = bx & 31;
  const int b    = m >> 1;
  const int lane = threadIdx.x & 63;
  const int wave = __builtin_amdgcn_readfirstlane(threadIdx.x >> 6);
  const int row  = rb * 64 + lane;

  const float4* lanePts = P4 + m * NPTS;
  const float4* loopPts = G4 + b * NPTS;
  const float*  gp      = Gp + m * NPTS;

  const float4 p  = lanePts[row];
  const float  Fi = F[m * NPTS + row];
  float c = 0.f;
  const int j0 = wave * (NPTS / 4);

  for (int jc = 0; jc < NPTS / 4; jc += 8) {
#pragma unroll
    for (int u = 0; u < 8; ++u) {
      const int j = j0 + jc + u;
      const float4 g = loopPts[j];
      float dot = p.x * g.x + p.y * g.y + p.z * g.z;
      float d = fmaxf(fmaf(-2.f, dot, p.w + g.w), 0.f);
      const float C = fsqrt_(d + 1e-12f);
      const float t = fmaf(-KSCALE, C, gp[j]);
      c = fmaf(fexp2(t + Fi), C, c);
    }
  }
#pragma unroll
  for (int o = 32; o; o >>= 1) c += __shfl_xor(c, o);
  __shared__ float sc[4];
  if (lane == 0) sc[wave] = c;
  __syncthreads();
  if (threadIdx.x == 0) atomicAdd(&cost[m], sc[0] + sc[1] + sc[2] + sc[3]);
}

__global__ void final_kernel(const float* __restrict__ cost,
                             const float* __restrict__ chamf,
                             float* __restrict__ out)
{
  if (blockIdx.x == 0 && threadIdx.x == 0) {
    float cs = 0.f;
    for (int i = 0; i < NMAT; ++i) cs += cost[i];
    // chamfer: (sum rowmins + sum colmins) / (B*N);  emd: (sum of 32 costs) / B
    out[0] = chamf[0] / (float)(BATCH * NPTS) + cs / (float)BATCH;
  }
}

extern "C" void kernel_launch(void* const* d_in, const int* in_sizes, int n_in,
                              void* d_out, int out_size, void* d_ws, size_t ws_size,
                              hipStream_t stream) {
  (void)in_sizes; (void)n_in; (void)out_size; (void)ws_size;
  const float* gt = (const float*)d_in[0];
  const float* p0 = (const float*)d_in[2];
  const float* p1 = (const float*)d_in[3];

  float* ws = (float*)d_ws;
  float4* P4 = (float4*)ws;                        // 32*2048 float4  = 262144 floats
  float4* G4 = (float4*)(ws + NMAT * NPTS * 4);    // 16*2048 float4  = 131072 floats
  float* F    = ws + NMAT * NPTS * 4 + BATCH * NPTS * 4;  // 65536
  float* Gp   = F + NMAT * NPTS;                           // 65536
  float* cost = Gp + NMAT * NPTS;                          // 32
  float* chamf = cost + NMAT;                              // 1

  const int initN = NMAT * NPTS + BATCH * NPTS + NMAT + 1;
  pack_kernel<<<(initN + 255) / 256, 256, 0, stream>>>(gt, p0, p1, P4, G4, cost, chamf);

  const int grid = NMAT * (NPTS / 64);  // 1024 workgroups

  // iteration 0: f-update sums over zero potential; both halves fuse chamfer mins
  sink_kernel<1, 1, 0><<<grid, 256, 0, stream>>>(P4, G4, Gp, F, chamf);
  sink_kernel<1, 0, 1><<<grid, 256, 0, stream>>>(P4, G4, F, Gp, chamf);
  for (int it = 1; it < ITERS; ++it) {
    sink_kernel<0, 0, 0><<<grid, 256, 0, stream>>>(P4, G4, Gp, F, chamf);
    sink_kernel<0, 0, 1><<<grid, 256, 0, stream>>>(P4, G4, F, Gp, chamf);
  }
  cost_kernel<<<grid, 256, 0, stream>>>(P4, G4, F, Gp, cost);
  final_kernel<<<1, 64, 0, stream>>>(cost, chamf, (float*)d_out);
}

// Round 2
// 2288.010 us; speedup vs baseline: 1.1712x; 1.1712x over previous
//
#include <hip/hip_runtime.h>

#define BATCH 16
#define NPTS  2048
#define NMAT  32   // 16 batches x 2 preds
#define ITERS 20
#define WAVES 8    // waves per workgroup (block = 64*WAVES)

__device__ __forceinline__ float fexp2(float x){ return __builtin_amdgcn_exp2f(x); }
__device__ __forceinline__ float flog2(float x){ return __builtin_amdgcn_logf(x); }
__device__ __forceinline__ float fsqrt_(float x){ return __builtin_amdgcn_sqrtf(x); }

// K = log2(e)/EPS, EPS = 0.05.  Potentials stored pre-scaled: F = f*K, G = g*K.
// f-update: F_i = -11 - M_i - log2(S_i),  y_ij = G_j - K*C_ij,
// M_i = max_j y_ij, S_i = sum_j 2^(y_ij - M_i).   (-11 = log2(1/2048))
constexpr float KSCALE = 28.853900817779268f;

__global__ void __launch_bounds__(256) pack_kernel(
    const float* __restrict__ gt, const float* __restrict__ p0, const float* __restrict__ p1,
    float4* __restrict__ P4, float4* __restrict__ G4,
    float* __restrict__ cost, float* __restrict__ chamf)
{
  int idx = blockIdx.x * 256 + threadIdx.x;
  if (idx < NMAT * NPTS) {
    int m = idx >> 11, i = idx & (NPTS - 1);
    int b = m >> 1;
    const float* s = (m & 1) ? p1 : p0;
    float x = s[(b * NPTS + i) * 3 + 0];
    float y = s[(b * NPTS + i) * 3 + 1];
    float z = s[(b * NPTS + i) * 3 + 2];
    P4[idx] = make_float4(x, y, z, x * x + y * y + z * z);
  } else if (idx < NMAT * NPTS + BATCH * NPTS) {
    int k = idx - NMAT * NPTS;
    float x = gt[k * 3 + 0], y = gt[k * 3 + 1], z = gt[k * 3 + 2];
    G4[k] = make_float4(x, y, z, x * x + y * y + z * z);
  } else if (idx < NMAT * NPTS + BATCH * NPTS + NMAT) {
    cost[idx - NMAT * NPTS - BATCH * NPTS] = 0.f;
  } else if (idx == NMAT * NPTS + BATCH * NPTS + NMAT) {
    chamf[0] = 0.f;
  }
}

// One Sinkhorn half-update over all 32 matrices.
// GSIDE=0: lanes = pred rows, loop over gt cols (f-update, writes F).
// GSIDE=1: lanes = gt cols, loop over pred rows (g-update, writes Gp).
// ZPOT: potential being summed over is identically zero (very first f-update).
// CHAM: also accumulate chamfer (min of squared dist along the loop axis).
template<int CHAM, int ZPOT, int GSIDE>
__global__ void __launch_bounds__(64 * WAVES) sink_kernel(
    const float4* __restrict__ P4, const float4* __restrict__ G4,
    const float* __restrict__ pot_in, float* __restrict__ pot_out,
    float* __restrict__ chamf)
{
  const int bx   = blockIdx.x;
  const int m    = bx >> 5;        // 32 row-blocks per matrix
  const int rb   = bx & 31;
  const int b    = m >> 1;
  const int lane = threadIdx.x & 63;
  const int wave = __builtin_amdgcn_readfirstlane(threadIdx.x >> 6);
  const int row  = rb * 64 + lane;

  const float4* lanePts = GSIDE ? (G4 + b * NPTS) : (P4 + m * NPTS);
  const float4* loopPts = GSIDE ? (P4 + m * NPTS) : (G4 + b * NPTS);
  const float*  pin     = pot_in + m * NPTS;

  const float4 p = lanePts[row];
  float mmax = -1e30f, s0 = 0.f, s1 = 0.f, dmin = 1e30f;
  const int j0 = wave * (NPTS / WAVES);

  for (int jc = 0; jc < NPTS / WAVES; jc += 8) {
    float t[8];
#pragma unroll
    for (int u = 0; u < 8; ++u) {
      const int j = j0 + jc + u;
      const float4 g = loopPts[j];
      float dot = p.x * g.x + p.y * g.y + p.z * g.z;
      float d = fmaxf(fmaf(-2.f, dot, p.w + g.w), 1e-12f);
      if (CHAM) dmin = fminf(dmin, d);
      const float C = fsqrt_(d);
      t[u] = ZPOT ? (-KSCALE * C) : fmaf(-KSCALE, C, pin[j]);
    }
    // max-tree in triples -> v_max3_f32
    float a0 = fmaxf(fmaxf(t[0], t[1]), t[2]);
    float a1 = fmaxf(fmaxf(t[3], t[4]), t[5]);
    float a2 = fmaxf(t[6], t[7]);
    float cm = fmaxf(fmaxf(a0, a1), a2);
    const float nm = fmaxf(mmax, cm);
    const float r = fexp2(mmax - nm);
    s0 *= r; s1 *= r;
#pragma unroll
    for (int u = 0; u < 8; u += 2) {
      s0 += fexp2(t[u] - nm);
      s1 += fexp2(t[u + 1] - nm);
    }
    mmax = nm;
  }
  float s = s0 + s1;

  // combine the WAVES column-split waves (log-domain merge), then write.
  __shared__ float sm[WAVES][64], ss[WAVES][64], sd[WAVES][64];
  sm[wave][lane] = mmax;
  ss[wave][lane] = s;
  if (CHAM) sd[wave][lane] = dmin;
  __syncthreads();
  if (wave == 0) {
    float M = sm[0][lane];
#pragma unroll
    for (int w = 1; w < WAVES; ++w) M = fmaxf(M, sm[w][lane]);
    float S = 0.f;
#pragma unroll
    for (int w = 0; w < WAVES; ++w) S += ss[w][lane] * fexp2(sm[w][lane] - M);
    pot_out[m * NPTS + row] = -11.0f - M - flog2(S);
    if (CHAM) {
      float dm = sd[0][lane];
#pragma unroll
      for (int w = 1; w < WAVES; ++w) dm = fminf(dm, sd[w][lane]);
#pragma unroll
      for (int o = 32; o; o >>= 1) dm += __shfl_xor(dm, o);
      if (lane == 0) atomicAdd(chamf, dm);
    }
  }
}

// cost_m = sum_ij 2^(F_i + G_j - K*C_ij) * C_ij
__global__ void __launch_bounds__(64 * WAVES) cost_kernel(
    const float4* __restrict__ P4, const float4* __restrict__ G4,
    const float* __restrict__ F, const float* __restrict__ Gp,
    float* __restrict__ cost)
{
  const int bx   = blockIdx.x;
  const int m    = bx >> 5;
  const int rb   = bx & 31;
  const int b    = m >> 1;
  const int lane = threadIdx.x & 63;
  const int wave = __builtin_amdgcn_readfirstlane(threadIdx.x >> 6);
  const int row  = rb * 64 + lane;

  const float4* lanePts = P4 + m * NPTS;
  const float4* loopPts = G4 + b * NPTS;
  const float*  gp      = Gp + m * NPTS;

  const float4 p  = lanePts[row];
  const float  Fi = F[m * NPTS + row];
  float c = 0.f;
  const int j0 = wave * (NPTS / WAVES);

  for (int jc = 0; jc < NPTS / WAVES; jc += 8) {
#pragma unroll
    for (int u = 0; u < 8; ++u) {
      const int j = j0 + jc + u;
      const float4 g = loopPts[j];
      float dot = p.x * g.x + p.y * g.y + p.z * g.z;
      float d = fmaxf(fmaf(-2.f, dot, p.w + g.w), 1e-12f);
      const float C = fsqrt_(d);
      const float t = fmaf(-KSCALE, C, gp[j]);
      c = fmaf(fexp2(t + Fi), C, c);
    }
  }
#pragma unroll
  for (int o = 32; o; o >>= 1) c += __shfl_xor(c, o);
  __shared__ float sc[WAVES];
  if (lane == 0) sc[wave] = c;
  __syncthreads();
  if (threadIdx.x == 0) {
    float t = 0.f;
#pragma unroll
    for (int w = 0; w < WAVES; ++w) t += sc[w];
    atomicAdd(&cost[m], t);
  }
}

__global__ void final_kernel(const float* __restrict__ cost,
                             const float* __restrict__ chamf,
                             float* __restrict__ out)
{
  if (blockIdx.x == 0 && threadIdx.x == 0) {
    float cs = 0.f;
    for (int i = 0; i < NMAT; ++i) cs += cost[i];
    out[0] = chamf[0] / (float)(BATCH * NPTS) + cs / (float)BATCH;
  }
}

extern "C" void kernel_launch(void* const* d_in, const int* in_sizes, int n_in,
                              void* d_out, int out_size, void* d_ws, size_t ws_size,
                              hipStream_t stream) {
  (void)in_sizes; (void)n_in; (void)out_size; (void)ws_size;
  const float* gt = (const float*)d_in[0];
  const float* p0 = (const float*)d_in[2];
  const float* p1 = (const float*)d_in[3];

  float* ws = (float*)d_ws;
  float4* P4 = (float4*)ws;                        // 32*2048 float4
  float4* G4 = (float4*)(ws + NMAT * NPTS * 4);    // 16*2048 float4
  float* F    = ws + NMAT * NPTS * 4 + BATCH * NPTS * 4;
  float* Gp   = F + NMAT * NPTS;
  float* cost = Gp + NMAT * NPTS;
  float* chamf = cost + NMAT;

  const int initN = NMAT * NPTS + BATCH * NPTS + NMAT + 1;
  pack_kernel<<<(initN + 255) / 256, 256, 0, stream>>>(gt, p0, p1, P4, G4, cost, chamf);

  const int grid = NMAT * (NPTS / 64);  // 1024 workgroups
  const int blk  = 64 * WAVES;

  sink_kernel<1, 1, 0><<<grid, blk, 0, stream>>>(P4, G4, Gp, F, chamf);
  sink_kernel<1, 0, 1><<<grid, blk, 0, stream>>>(P4, G4, F, Gp, chamf);
  for (int it = 1; it < ITERS; ++it) {
    sink_kernel<0, 0, 0><<<grid, blk, 0, stream>>>(P4, G4, Gp, F, chamf);
    sink_kernel<0, 0, 1><<<grid, blk, 0, stream>>>(P4, G4, F, Gp, chamf);
  }
  cost_kernel<<<grid, blk, 0, stream>>>(P4, G4, F, Gp, cost);
  final_kernel<<<1, 64, 0, stream>>>(cost, chamf, (float*)d_out);
}

// Round 3
// 1787.126 us; speedup vs baseline: 1.4994x; 1.2803x over previous
//
#include <hip/hip_runtime.h>

#define BATCH 16
#define NPTS  2048
#define NMAT  32   // 16 batches x 2 preds
#define ITERS 20
#define WAVES 8    // waves per workgroup (block = 64*WAVES)

__device__ __forceinline__ float fexp2(float x){ return __builtin_amdgcn_exp2f(x); }
__device__ __forceinline__ float flog2(float x){ return __builtin_amdgcn_logf(x); }
__device__ __forceinline__ float fsqrt_(float x){ return __builtin_amdgcn_sqrtf(x); }

// K = log2(e)/EPS, EPS = 0.05.  Potentials pre-scaled: F = f*K, G = g*K.
// LSE shift = the row's own previous potential (guaranteed safe by the
// Sinkhorn marginal constraint: every term 2^(pin_j - K*C + myold) <= 2^-11).
constexpr float KSCALE = 28.853900817779268f;

// P4: raw pred points (x,y,z,|p|^2).  G4: gt scaled (-2x,-2y,-2z,|g|^2+1e-12).
// d_ij = p.w + g.w + dot(g4.xyz, p.xyz)  (exactly one -2 in every product).
__global__ void __launch_bounds__(256) pack_kernel(
    const float* __restrict__ gt, const float* __restrict__ p0, const float* __restrict__ p1,
    float4* __restrict__ P4, float4* __restrict__ G4,
    float* __restrict__ cost, float* __restrict__ chamf)
{
  int idx = blockIdx.x * 256 + threadIdx.x;
  if (idx < NMAT * NPTS) {
    int m = idx >> 11, i = idx & (NPTS - 1);
    int b = m >> 1;
    const float* s = (m & 1) ? p1 : p0;
    float x = s[(b * NPTS + i) * 3 + 0];
    float y = s[(b * NPTS + i) * 3 + 1];
    float z = s[(b * NPTS + i) * 3 + 2];
    P4[idx] = make_float4(x, y, z, x * x + y * y + z * z);
  } else if (idx < NMAT * NPTS + BATCH * NPTS) {
    int k = idx - NMAT * NPTS;
    float x = gt[k * 3 + 0], y = gt[k * 3 + 1], z = gt[k * 3 + 2];
    G4[k] = make_float4(-2.f * x, -2.f * y, -2.f * z,
                        x * x + y * y + z * z + 1e-12f);
  } else if (idx < NMAT * NPTS + BATCH * NPTS + NMAT) {
    cost[idx - NMAT * NPTS - BATCH * NPTS] = 0.f;
  } else if (idx == NMAT * NPTS + BATCH * NPTS + NMAT) {
    chamf[0] = 0.f;
  }
}

// One Sinkhorn half-update over all 32 matrices.
// GSIDE=0: lanes = pred rows, loop over gt cols (writes F).
// GSIDE=1: lanes = gt cols, loop over pred rows (writes G).
// MODE=0: pin==0 and shift==0 (iter-0 f-update).
// MODE=1: read pin, shift==0   (iter-0 g-update).
// MODE=2: read pin, shift = own previous potential.
// CHAM: also accumulate chamfer (min squared dist along the loop axis).
template<int CHAM, int MODE, int GSIDE>
__global__ void __launch_bounds__(64 * WAVES) sink_kernel(
    const float4* __restrict__ P4, const float4* __restrict__ G4,
    const float* __restrict__ pot_in, float* __restrict__ pot_out,
    float* __restrict__ chamf)
{
  const int bx   = blockIdx.x;
  const int m    = bx >> 5;        // 32 row-blocks per matrix
  const int rb   = bx & 31;
  const int b    = m >> 1;
  const int lane = threadIdx.x & 63;
  const int wave = __builtin_amdgcn_readfirstlane(threadIdx.x >> 6);
  const int row  = rb * 64 + lane;

  const float4* lanePts = GSIDE ? (G4 + b * NPTS) : (P4 + m * NPTS);
  const float4* loopPts = GSIDE ? (P4 + m * NPTS) : (G4 + b * NPTS);
  const float*  pin     = pot_in + m * NPTS;

  const float4 p = lanePts[row];
  const float myold = (MODE == 2) ? pot_out[m * NPTS + row] : 0.f;
  float s0 = 0.f, s1 = 0.f, s2 = 0.f, s3 = 0.f, dmin = 1e30f;
  const int j0 = wave * (NPTS / WAVES);

  for (int jc = 0; jc < NPTS / WAVES; jc += 8) {
#pragma unroll
    for (int u = 0; u < 8; ++u) {
      const int j = j0 + jc + u;
      const float4 g = loopPts[j];
      float acc = fmaf(g.x, p.x, p.w);
      acc = fmaf(g.y, p.y, acc);
      acc = fmaf(g.z, p.z, acc);
      const float d = acc + g.w;
      if (CHAM) dmin = fminf(dmin, d);
      const float C = fsqrt_(d);
      float e;
      if (MODE == 0)      e = -KSCALE * C;
      else if (MODE == 1) e = fmaf(-KSCALE, C, pin[j]);
      else                e = fmaf(-KSCALE, C, pin[j]) + myold;
      const float x = fexp2(e);
      if ((u & 3) == 0) s0 += x;
      else if ((u & 3) == 1) s1 += x;
      else if ((u & 3) == 2) s2 += x;
      else s3 += x;
    }
  }
  const float s = (s0 + s1) + (s2 + s3);

  // combine the WAVES column-split partial sums, then write.
  __shared__ float ss[WAVES][64], sd[WAVES][64];
  ss[wave][lane] = s;
  if (CHAM) sd[wave][lane] = dmin;
  __syncthreads();
  if (wave == 0) {
    float S = 0.f;
#pragma unroll
    for (int w = 0; w < WAVES; ++w) S += ss[w][lane];
    pot_out[m * NPTS + row] = ((MODE == 2) ? myold : 0.f) - 11.0f - flog2(S);
    if (CHAM) {
      float dm = sd[0][lane];
#pragma unroll
      for (int w = 1; w < WAVES; ++w) dm = fminf(dm, sd[w][lane]);
#pragma unroll
      for (int o = 32; o; o >>= 1) dm += __shfl_xor(dm, o);
      if (lane == 0) atomicAdd(chamf, dm);
    }
  }
}

// cost_m = sum_ij 2^(F_i + G_j - K*C_ij) * C_ij   (terms <= 2^-11 * C, safe)
__global__ void __launch_bounds__(64 * WAVES) cost_kernel(
    const float4* __restrict__ P4, const float4* __restrict__ G4,
    const float* __restrict__ F, const float* __restrict__ Gp,
    float* __restrict__ cost)
{
  const int bx   = blockIdx.x;
  const int m    = bx >> 5;
  const int rb   = bx & 31;
  const int b    = m >> 1;
  const int lane = threadIdx.x & 63;
  const int wave = __builtin_amdgcn_readfirstlane(threadIdx.x >> 6);
  const int row  = rb * 64 + lane;

  const float4* lanePts = P4 + m * NPTS;
  const float4* loopPts = G4 + b * NPTS;
  const float*  gp      = Gp + m * NPTS;

  const float4 p  = lanePts[row];
  const float  Fi = F[m * NPTS + row];
  float c0 = 0.f, c1 = 0.f;
  const int j0 = wave * (NPTS / WAVES);

  for (int jc = 0; jc < NPTS / WAVES; jc += 8) {
#pragma unroll
    for (int u = 0; u < 8; ++u) {
      const int j = j0 + jc + u;
      const float4 g = loopPts[j];
      float acc = fmaf(g.x, p.x, p.w);
      acc = fmaf(g.y, p.y, acc);
      acc = fmaf(g.z, p.z, acc);
      const float d = acc + g.w;
      const float C = fsqrt_(d);
      const float e = fmaf(-KSCALE, C, gp[j]) + Fi;
      if (u & 1) c1 = fmaf(fexp2(e), C, c1);
      else       c0 = fmaf(fexp2(e), C, c0);
    }
  }
  float c = c0 + c1;
#pragma unroll
  for (int o = 32; o; o >>= 1) c += __shfl_xor(c, o);
  __shared__ float sc[WAVES];
  if (lane == 0) sc[wave] = c;
  __syncthreads();
  if (threadIdx.x == 0) {
    float t = 0.f;
#pragma unroll
    for (int w = 0; w < WAVES; ++w) t += sc[w];
    atomicAdd(&cost[m], t);
  }
}

__global__ void final_kernel(const float* __restrict__ cost,
                             const float* __restrict__ chamf,
                             float* __restrict__ out)
{
  if (blockIdx.x == 0 && threadIdx.x == 0) {
    float cs = 0.f;
    for (int i = 0; i < NMAT; ++i) cs += cost[i];
    out[0] = chamf[0] / (float)(BATCH * NPTS) + cs / (float)BATCH;
  }
}

extern "C" void kernel_launch(void* const* d_in, const int* in_sizes, int n_in,
                              void* d_out, int out_size, void* d_ws, size_t ws_size,
                              hipStream_t stream) {
  (void)in_sizes; (void)n_in; (void)out_size; (void)ws_size;
  const float* gt = (const float*)d_in[0];
  const float* p0 = (const float*)d_in[2];
  const float* p1 = (const float*)d_in[3];

  float* ws = (float*)d_ws;
  float4* P4 = (float4*)ws;                        // 32*2048 float4
  float4* G4 = (float4*)(ws + NMAT * NPTS * 4);    // 16*2048 float4
  float* F    = ws + NMAT * NPTS * 4 + BATCH * NPTS * 4;
  float* Gp   = F + NMAT * NPTS;
  float* cost = Gp + NMAT * NPTS;
  float* chamf = cost + NMAT;

  const int initN = NMAT * NPTS + BATCH * NPTS + NMAT + 1;
  pack_kernel<<<(initN + 255) / 256, 256, 0, stream>>>(gt, p0, p1, P4, G4, cost, chamf);

  const int grid = NMAT * (NPTS / 64);  // 1024 workgroups
  const int blk  = 64 * WAVES;

  // iter 0: f-update (pin==0, shift 0) and g-update (pin=F, shift 0); both fuse chamfer
  sink_kernel<1, 0, 0><<<grid, blk, 0, stream>>>(P4, G4, Gp, F, chamf);
  sink_kernel<1, 1, 1><<<grid, blk, 0, stream>>>(P4, G4, F, Gp, chamf);
  for (int it = 1; it < ITERS; ++it) {
    sink_kernel<0, 2, 0><<<grid, blk, 0, stream>>>(P4, G4, Gp, F, chamf);
    sink_kernel<0, 2, 1><<<grid, blk, 0, stream>>>(P4, G4, F, Gp, chamf);
  }
  cost_kernel<<<grid, blk, 0, stream>>>(P4, G4, F, Gp, cost);
  final_kernel<<<1, 64, 0, stream>>>(cost, chamf, (float*)d_out);
}

// Round 5
// 1732.240 us; speedup vs baseline: 1.5469x; 1.0317x over previous
//
#include <hip/hip_runtime.h>

#define BATCH 16
#define NPTS  2048
#define NMAT  32   // 16 batches x 2 preds
#define ITERS 20

typedef short bf16x8 __attribute__((ext_vector_type(8)));
typedef float f32x4 __attribute__((ext_vector_type(4)));
typedef unsigned short ushort_t;
typedef unsigned int uint_t;

// K = log2(e)/EPS, EPS = 0.05. Potentials pre-scaled: F = f*K.
constexpr float KSCALE = 28.853900817779268f;

__device__ __forceinline__ float fexp2(float x){ return __builtin_amdgcn_exp2f(x); }
__device__ __forceinline__ float flog2(float x){ return __builtin_amdgcn_logf(x); }
__device__ __forceinline__ float fsqrt_(float x){ return __builtin_amdgcn_sqrtf(x); }

__device__ __forceinline__ ushort_t bfr16(float x){
  uint_t u = __float_as_uint(x);
  return (ushort_t)((u + 0x7FFFu + ((u >> 16) & 1u)) >> 16);
}
__device__ __forceinline__ float bfrf(float x){
  return __uint_as_float(((uint_t)bfr16(x)) << 16);
}

// Per-point MFMA fragment encodings (27 used slots of K=32), bf16:
// per component c: L=[nh,nm,nl, 1,1,1, -2ah,-2ah,-2al], R=[1,1,1, nh,nm,nl, bh,bl,bh]
// sum_k L_k(p) * R_k(g) = |p|^2 + |g|^2 - 2(ah*bh + ah*bl + al*bh) ~= ||p-g||^2
// Storage per cloud: 128 tiles x 1KB; lane l of tile t reads 16B at t*1024 + l*16
// holding point (l&15)'s slots (l>>4)*8 .. +7  (A and B use identical layout,
// so slot-s-of-A pairs with slot-s-of-B under any symmetric hardware k map).
__device__ __forceinline__ void store_enc(ushort_t* base, int pt, const ushort_t* enc){
  ushort_t* p = base + (pt >> 4) * 512 + (pt & 15) * 8;
#pragma unroll
  for (int g = 0; g < 4; ++g){
    *reinterpret_cast<ushort4*>(p + g*128)     = make_ushort4(enc[g*8+0],enc[g*8+1],enc[g*8+2],enc[g*8+3]);
    *reinterpret_cast<ushort4*>(p + g*128 + 4) = make_ushort4(enc[g*8+4],enc[g*8+5],enc[g*8+6],enc[g*8+7]);
  }
}

__global__ void __launch_bounds__(256) pack_kernel(
    const float* __restrict__ gt, const float* __restrict__ p0, const float* __restrict__ p1,
    ushort_t* __restrict__ Lpred, ushort_t* __restrict__ Rpred,
    ushort_t* __restrict__ Lgt,   ushort_t* __restrict__ Rgt,
    float* __restrict__ cost, float* __restrict__ chamf)
{
  const int idx = blockIdx.x * 256 + threadIdx.x;
  const int totalPts = (NMAT + BATCH) * NPTS;
  if (idx < totalPts) {
    const int cl = idx >> 11, pt = idx & (NPTS - 1);
    const float* src; ushort_t *Lb, *Rb;
    if (cl < NMAT) {
      const int b = cl >> 1;
      src = ((cl & 1) ? p1 : p0) + (b * NPTS + pt) * 3;
      Lb = Lpred + cl * 65536; Rb = Rpred + cl * 65536;
    } else {
      const int b = cl - NMAT;
      src = gt + (b * NPTS + pt) * 3;
      Lb = Lgt + b * 65536; Rb = Rgt + b * 65536;
    }
    float L[32], R[32];
#pragma unroll
    for (int k = 27; k < 32; ++k){ L[k] = 0.f; R[k] = 0.f; }
#pragma unroll
    for (int c = 0; c < 3; ++c){
      const float v  = src[c];
      const float ah = bfrf(v), al = bfrf(v - ah);
      const float n2 = v * v;
      const float nh = bfrf(n2); const float r1 = n2 - nh;
      const float nm = bfrf(r1); const float nl = bfrf(r1 - nm);
      const int B0 = c * 9;
      L[B0+0]=nh;  L[B0+1]=nm;  L[B0+2]=nl;
      L[B0+3]=1.f; L[B0+4]=1.f; L[B0+5]=1.f;
      L[B0+6]=-2.f*ah; L[B0+7]=-2.f*ah; L[B0+8]=-2.f*al;
      R[B0+0]=1.f; R[B0+1]=1.f; R[B0+2]=1.f;
      R[B0+3]=nh;  R[B0+4]=nm;  R[B0+5]=nl;
      R[B0+6]=ah;  R[B0+7]=al;  R[B0+8]=ah;
    }
    ushort_t Le[32], Re[32];
#pragma unroll
    for (int k = 0; k < 32; ++k){ Le[k] = bfr16(L[k]); Re[k] = bfr16(R[k]); }
    store_enc(Lb, pt, Le);
    store_enc(Rb, pt, Re);
  } else if (idx < totalPts + NMAT) {
    cost[idx - totalPts] = 0.f;
  } else if (idx == totalPts + NMAT) {
    chamf[0] = 0.f;
  }
}

// One Sinkhorn half-update over all 32 matrices via MFMA distance tiles.
// Block = 512 thr = 8 waves; each wave owns 16 complete rows (all 2048 cols).
// GSIDE=0: rows=pred (writes F); GSIDE=1: rows=gt (writes G).
// MODE=0: pin==0, no shift; MODE=1: read pin, no shift; MODE=2: pin + own-old shift.
template<int CHAM, int MODE, int GSIDE>
__global__ void __launch_bounds__(512) sink_kernel(
    const ushort_t* __restrict__ Lpred, const ushort_t* __restrict__ Rpred,
    const ushort_t* __restrict__ Lgt,   const ushort_t* __restrict__ Rgt,
    float* __restrict__ F, float* __restrict__ G, float* __restrict__ chamf)
{
  const int bx = blockIdx.x;
  const int m  = bx >> 4;
  const int rb = bx & 15;
  const int b  = m >> 1;
  const int tid = threadIdx.x;
  const int l  = tid & 63;
  const int w  = tid >> 6;

  const ushort_t* A  = GSIDE ? (Lgt + b*65536)   : (Lpred + m*65536);
  const ushort_t* Bm = GSIDE ? (Rpred + m*65536) : (Rgt + b*65536);
  const float* pin = (GSIDE ? F : G) + m*NPTS;   // column potentials
  float*       pout = (GSIDE ? G : F) + m*NPTS;  // row potentials

  const int rowbase = rb*128 + w*16;

  __shared__ float spot[NPTS];
  __shared__ ushort_t stg[2][4096];

  if (MODE != 0) {
    for (int i = tid; i < NPTS; i += 512) spot[i] = pin[i];
  }

  const bf16x8 af = *reinterpret_cast<const bf16x8*>(A + (rowbase>>4)*512 + l*8);

  float myold0=0.f, myold1=0.f, myold2=0.f, myold3=0.f;
  if (MODE == 2) {
    const int rg = rowbase + ((l>>4)<<2);
    myold0 = pout[rg+0]; myold1 = pout[rg+1]; myold2 = pout[rg+2]; myold3 = pout[rg+3];
  }

  float s0=0.f,s1=0.f,s2=0.f,s3=0.f;
  float d0=1e30f,d1=1e30f,d2=1e30f,d3=1e30f;
  const f32x4 zz = {0.f,0.f,0.f,0.f};

  float4 pre = *reinterpret_cast<const float4*>(Bm + tid*8);
  for (int ch = 0; ch < 16; ++ch){
    *reinterpret_cast<float4*>(&stg[ch&1][tid*8]) = pre;
    if (ch < 15) pre = *reinterpret_cast<const float4*>(Bm + (ch+1)*4096 + tid*8);
    __syncthreads();
    const ushort_t* sb = stg[ch&1];
#pragma unroll
    for (int tt = 0; tt < 8; ++tt){
      const int t = ch*8 + tt;
      const bf16x8 bf = *reinterpret_cast<const bf16x8*>(sb + tt*512 + l*8);
      f32x4 d4 = __builtin_amdgcn_mfma_f32_16x16x32_bf16(af, bf, zz, 0, 0, 0);
      const float pv = (MODE != 0) ? spot[t*16 + (l&15)] : 0.f;
      const float da = fmaxf(d4[0],1e-12f), db = fmaxf(d4[1],1e-12f);
      const float dc = fmaxf(d4[2],1e-12f), dd = fmaxf(d4[3],1e-12f);
      if (CHAM){ d0=fminf(d0,da); d1=fminf(d1,db); d2=fminf(d2,dc); d3=fminf(d3,dd); }
      const float Ca=fsqrt_(da), Cb=fsqrt_(db), Cc=fsqrt_(dc), Cd=fsqrt_(dd);
      float ea, eb, ec, ed;
      if (MODE == 0){ ea=-KSCALE*Ca; eb=-KSCALE*Cb; ec=-KSCALE*Cc; ed=-KSCALE*Cd; }
      else if (MODE == 1){
        ea=fmaf(-KSCALE,Ca,pv); eb=fmaf(-KSCALE,Cb,pv);
        ec=fmaf(-KSCALE,Cc,pv); ed=fmaf(-KSCALE,Cd,pv);
      } else {
        ea=fmaf(-KSCALE,Ca,pv)+myold0; eb=fmaf(-KSCALE,Cb,pv)+myold1;
        ec=fmaf(-KSCALE,Cc,pv)+myold2; ed=fmaf(-KSCALE,Cd,pv)+myold3;
      }
      s0 += fexp2(ea); s1 += fexp2(eb); s2 += fexp2(ec); s3 += fexp2(ed);
    }
    __syncthreads();
  }

  // reduce across the 16 lanes (columns) sharing each row
#pragma unroll
  for (int o = 1; o < 16; o <<= 1){
    s0 += __shfl_xor(s0,o); s1 += __shfl_xor(s1,o);
    s2 += __shfl_xor(s2,o); s3 += __shfl_xor(s3,o);
    if (CHAM){
      d0 = fminf(d0,__shfl_xor(d0,o)); d1 = fminf(d1,__shfl_xor(d1,o));
      d2 = fminf(d2,__shfl_xor(d2,o)); d3 = fminf(d3,__shfl_xor(d3,o));
    }
  }
  if ((l & 15) == 0){
    const int rg = rowbase + ((l>>4)<<2);
    pout[rg+0] = ((MODE==2)?myold0:0.f) - 11.0f - flog2(s0);
    pout[rg+1] = ((MODE==2)?myold1:0.f) - 11.0f - flog2(s1);
    pout[rg+2] = ((MODE==2)?myold2:0.f) - 11.0f - flog2(s2);
    pout[rg+3] = ((MODE==2)?myold3:0.f) - 11.0f - flog2(s3);
  }
  if (CHAM){
    float v = ((l & 15) == 0) ? ((d0+d1)+(d2+d3)) : 0.f;
    v += __shfl_xor(v,16); v += __shfl_xor(v,32);
    if (l == 0) atomicAdd(chamf, v);
  }
}

// cost_m = sum_ij 2^(F_i + G_j - K*C_ij) * C_ij
__global__ void __launch_bounds__(512) cost_kernel(
    const ushort_t* __restrict__ Lpred, const ushort_t* __restrict__ Rgt,
    const float* __restrict__ F, const float* __restrict__ G,
    float* __restrict__ cost)
{
  const int bx = blockIdx.x;
  const int m = bx >> 4, rb = bx & 15, b = m >> 1;
  const int tid = threadIdx.x, l = tid & 63, w = tid >> 6;
  const ushort_t* A  = Lpred + m*65536;
  const ushort_t* Bm = Rgt + b*65536;
  const float* pin = G + m*NPTS;
  const float* Fm  = F + m*NPTS;   // FIX: row potentials offset by matrix
  const int rowbase = rb*128 + w*16;

  __shared__ float spot[NPTS];
  __shared__ ushort_t stg[2][4096];
  for (int i = tid; i < NPTS; i += 512) spot[i] = pin[i];

  const bf16x8 af = *reinterpret_cast<const bf16x8*>(A + (rowbase>>4)*512 + l*8);
  const int rg = rowbase + ((l>>4)<<2);
  const float F0=Fm[rg+0], F1=Fm[rg+1], F2=Fm[rg+2], F3=Fm[rg+3];
  float c0=0.f,c1=0.f,c2=0.f,c3=0.f;
  const f32x4 zz = {0.f,0.f,0.f,0.f};

  float4 pre = *reinterpret_cast<const float4*>(Bm + tid*8);
  for (int ch = 0; ch < 16; ++ch){
    *reinterpret_cast<float4*>(&stg[ch&1][tid*8]) = pre;
    if (ch < 15) pre = *reinterpret_cast<const float4*>(Bm + (ch+1)*4096 + tid*8);
    __syncthreads();
    const ushort_t* sb = stg[ch&1];
#pragma unroll
    for (int tt = 0; tt < 8; ++tt){
      const int t = ch*8 + tt;
      const bf16x8 bf = *reinterpret_cast<const bf16x8*>(sb + tt*512 + l*8);
      f32x4 d4 = __builtin_amdgcn_mfma_f32_16x16x32_bf16(af, bf, zz, 0, 0, 0);
      const float pv = spot[t*16 + (l&15)];
      const float da = fmaxf(d4[0],1e-12f), db = fmaxf(d4[1],1e-12f);
      const float dc = fmaxf(d4[2],1e-12f), dd = fmaxf(d4[3],1e-12f);
      const float Ca=fsqrt_(da), Cb=fsqrt_(db), Cc=fsqrt_(dc), Cd=fsqrt_(dd);
      c0 = fmaf(fexp2(fmaf(-KSCALE,Ca,pv)+F0), Ca, c0);
      c1 = fmaf(fexp2(fmaf(-KSCALE,Cb,pv)+F1), Cb, c1);
      c2 = fmaf(fexp2(fmaf(-KSCALE,Cc,pv)+F2), Cc, c2);
      c3 = fmaf(fexp2(fmaf(-KSCALE,Cd,pv)+F3), Cd, c3);
    }
    __syncthreads();
  }
  float c = (c0+c1)+(c2+c3);
#pragma unroll
  for (int o = 1; o < 64; o <<= 1) c += __shfl_xor(c,o);
  if (l == 0) atomicAdd(&cost[m], c);
}

__global__ void final_kernel(const float* __restrict__ cost,
                             const float* __restrict__ chamf,
                             float* __restrict__ out)
{
  if (blockIdx.x == 0 && threadIdx.x == 0) {
    float cs = 0.f;
    for (int i = 0; i < NMAT; ++i) cs += cost[i];
    out[0] = chamf[0] / (float)(BATCH * NPTS) + cs / (float)BATCH;
  }
}

extern "C" void kernel_launch(void* const* d_in, const int* in_sizes, int n_in,
                              void* d_out, int out_size, void* d_ws, size_t ws_size,
                              hipStream_t stream) {
  (void)in_sizes; (void)n_in; (void)out_size; (void)ws_size;
  const float* gt = (const float*)d_in[0];
  const float* p0 = (const float*)d_in[2];
  const float* p1 = (const float*)d_in[3];

  // ws layout (ushort units for frag arrays; 65536 ush = 128KB per cloud)
  ushort_t* Lpred = (ushort_t*)d_ws;                  // 32 clouds -> 4MB
  ushort_t* Rpred = Lpred + NMAT * 65536;             // 4MB
  ushort_t* Lgt   = Rpred + NMAT * 65536;             // 2MB
  ushort_t* Rgt   = Lgt + BATCH * 65536;              // 2MB
  float* F     = (float*)(Rgt + BATCH * 65536);       // 32*2048
  float* G     = F + NMAT * NPTS;                     // 32*2048
  float* cost  = G + NMAT * NPTS;                     // 32
  float* chamf = cost + NMAT;                         // 1

  const int initN = (NMAT + BATCH) * NPTS + NMAT + 1;
  pack_kernel<<<(initN + 255) / 256, 256, 0, stream>>>(gt, p0, p1, Lpred, Rpred, Lgt, Rgt, cost, chamf);

  const int grid = NMAT * 16;   // 512 blocks, 8 waves each, 16 rows/wave
  sink_kernel<1, 0, 0><<<grid, 512, 0, stream>>>(Lpred, Rpred, Lgt, Rgt, F, G, chamf);
  sink_kernel<1, 1, 1><<<grid, 512, 0, stream>>>(Lpred, Rpred, Lgt, Rgt, F, G, chamf);
  for (int it = 1; it < ITERS; ++it) {
    sink_kernel<0, 2, 0><<<grid, 512, 0, stream>>>(Lpred, Rpred, Lgt, Rgt, F, G, chamf);
    sink_kernel<0, 2, 1><<<grid, 512, 0, stream>>>(Lpred, Rpred, Lgt, Rgt, F, G, chamf);
  }
  cost_kernel<<<grid, 512, 0, stream>>>(Lpred, Rgt, F, G, cost);
  final_kernel<<<1, 64, 0, stream>>>(cost, chamf, (float*)d_out);
}

// Round 6
// 1518.492 us; speedup vs baseline: 1.7647x; 1.1408x over previous
//
#include <hip/hip_runtime.h>

#define BATCH 16
#define NPTS  2048
#define NMAT  32   // 16 batches x 2 preds
#define ITERS 20

typedef short bf16x8 __attribute__((ext_vector_type(8)));
typedef float f32x4 __attribute__((ext_vector_type(4)));
typedef unsigned short ushort_t;
typedef unsigned int uint_t;

// K = log2(e)/EPS, EPS = 0.05. Potentials pre-scaled: F = f*K.
constexpr float KSCALE = 28.853900817779268f;

__device__ __forceinline__ float fexp2(float x){ return __builtin_amdgcn_exp2f(x); }
__device__ __forceinline__ float flog2(float x){ return __builtin_amdgcn_logf(x); }
__device__ __forceinline__ float fsqrt_(float x){ return __builtin_amdgcn_sqrtf(x); }

__device__ __forceinline__ ushort_t bfr16(float x){
  uint_t u = __float_as_uint(x);
  return (ushort_t)((u + 0x7FFFu + ((u >> 16) & 1u)) >> 16);
}
__device__ __forceinline__ float bfrf(float x){
  return __uint_as_float(((uint_t)bfr16(x)) << 16);
}

// Per-point MFMA fragment encodings (27 used slots of K=32), bf16:
// per component c: L=[nh,nm,nl, 1,1,1, -2ah,-2ah,-2al], R=[1,1,1, nh,nm,nl, bh,bl,bh]
// sum_k L_k(p) * R_k(g) = |p|^2 + |g|^2 - 2(ah*bh + ah*bl + al*bh) ~= ||p-g||^2
// Storage per cloud: 128 tiles x 1KB; lane l of tile t reads 16B at t*1024 + l*16
// holding point (l&15)'s slots (l>>4)*8 .. +7  (A and B use identical layout,
// so slot-s-of-A pairs with slot-s-of-B under any symmetric hardware k map).
__device__ __forceinline__ void store_enc(ushort_t* base, int pt, const ushort_t* enc){
  ushort_t* p = base + (pt >> 4) * 512 + (pt & 15) * 8;
#pragma unroll
  for (int g = 0; g < 4; ++g){
    *reinterpret_cast<ushort4*>(p + g*128)     = make_ushort4(enc[g*8+0],enc[g*8+1],enc[g*8+2],enc[g*8+3]);
    *reinterpret_cast<ushort4*>(p + g*128 + 4) = make_ushort4(enc[g*8+4],enc[g*8+5],enc[g*8+6],enc[g*8+7]);
  }
}

__global__ void __launch_bounds__(256) pack_kernel(
    const float* __restrict__ gt, const float* __restrict__ p0, const float* __restrict__ p1,
    ushort_t* __restrict__ Lpred, ushort_t* __restrict__ Rpred,
    ushort_t* __restrict__ Lgt,   ushort_t* __restrict__ Rgt,
    float* __restrict__ cost, float* __restrict__ chamf)
{
  const int idx = blockIdx.x * 256 + threadIdx.x;
  const int totalPts = (NMAT + BATCH) * NPTS;
  if (idx < totalPts) {
    const int cl = idx >> 11, pt = idx & (NPTS - 1);
    const float* src; ushort_t *Lb, *Rb;
    if (cl < NMAT) {
      const int b = cl >> 1;
      src = ((cl & 1) ? p1 : p0) + (b * NPTS + pt) * 3;
      Lb = Lpred + cl * 65536; Rb = Rpred + cl * 65536;
    } else {
      const int b = cl - NMAT;
      src = gt + (b * NPTS + pt) * 3;
      Lb = Lgt + b * 65536; Rb = Rgt + b * 65536;
    }
    float L[32], R[32];
#pragma unroll
    for (int k = 27; k < 32; ++k){ L[k] = 0.f; R[k] = 0.f; }
#pragma unroll
    for (int c = 0; c < 3; ++c){
      const float v  = src[c];
      const float ah = bfrf(v), al = bfrf(v - ah);
      const float n2 = v * v;
      const float nh = bfrf(n2); const float r1 = n2 - nh;
      const float nm = bfrf(r1); const float nl = bfrf(r1 - nm);
      const int B0 = c * 9;
      L[B0+0]=nh;  L[B0+1]=nm;  L[B0+2]=nl;
      L[B0+3]=1.f; L[B0+4]=1.f; L[B0+5]=1.f;
      L[B0+6]=-2.f*ah; L[B0+7]=-2.f*ah; L[B0+8]=-2.f*al;
      R[B0+0]=1.f; R[B0+1]=1.f; R[B0+2]=1.f;
      R[B0+3]=nh;  R[B0+4]=nm;  R[B0+5]=nl;
      R[B0+6]=ah;  R[B0+7]=al;  R[B0+8]=ah;
    }
    ushort_t Le[32], Re[32];
#pragma unroll
    for (int k = 0; k < 32; ++k){ Le[k] = bfr16(L[k]); Re[k] = bfr16(R[k]); }
    store_enc(Lb, pt, Le);
    store_enc(Rb, pt, Re);
  } else if (idx < totalPts + NMAT) {
    cost[idx - totalPts] = 0.f;
  } else if (idx == totalPts + NMAT) {
    chamf[0] = 0.f;
  }
}

// One Sinkhorn half-update over all 32 matrices via MFMA distance tiles.
// Grid = NMAT*32; block = 512 thr = 8 waves = 4 row-waves x 2 col-halves.
// Block owns 64 rows; wave (w&3) owns rows rowbase+(w&3)*16, cols half*1024..
// B fragments read directly from global (L1/L2-resident) - no main-loop barriers.
// GSIDE=0: rows=pred (writes F); GSIDE=1: rows=gt (writes G).
// MODE=0: pin==0, no shift; MODE=1: read pin, no shift; MODE=2: pin + own-old shift.
template<int CHAM, int MODE, int GSIDE>
__global__ void __launch_bounds__(512, 8) sink_kernel(
    const ushort_t* __restrict__ Lpred, const ushort_t* __restrict__ Rpred,
    const ushort_t* __restrict__ Lgt,   const ushort_t* __restrict__ Rgt,
    float* __restrict__ F, float* __restrict__ G, float* __restrict__ chamf)
{
  const int bx = blockIdx.x;
  const int m   = bx >> 5;
  const int rg5 = bx & 31;
  const int b   = m >> 1;
  const int tid = threadIdx.x;
  const int l   = tid & 63;
  const int w   = __builtin_amdgcn_readfirstlane(tid >> 6);
  const int wr  = w & 3;
  const int half= w >> 2;

  const ushort_t* A  = GSIDE ? (Lgt + b*65536)   : (Lpred + m*65536);
  const ushort_t* Bm = GSIDE ? (Rpred + m*65536) : (Rgt + b*65536);
  const float* pin  = (GSIDE ? F : G) + m*NPTS;   // column potentials
  float*       pout = (GSIDE ? G : F) + m*NPTS;   // row potentials

  const int rowbase = rg5 * 64;
  const int myrow16 = rowbase + wr * 16;

  __shared__ float spot[NPTS];
  __shared__ float ssum[8][16];
  __shared__ float sdm[8][16];
  __shared__ float sds[4];

  if (MODE != 0) {
    for (int i = tid; i < NPTS; i += 512) spot[i] = pin[i];
    __syncthreads();
  }

  const bf16x8 af = *reinterpret_cast<const bf16x8*>(A + (myrow16 >> 4) * 512 + l * 8);

  float my0=0.f,my1=0.f,my2=0.f,my3=0.f;
  if (MODE == 2) {
    const int rg = myrow16 + ((l >> 4) << 2);
    my0 = pout[rg+0]; my1 = pout[rg+1]; my2 = pout[rg+2]; my3 = pout[rg+3];
  }

  float s0=0.f,s1=0.f,s2=0.f,s3=0.f;
  float d0=1e30f,d1=1e30f,d2=1e30f,d3=1e30f;
  const f32x4 zz = {0.f,0.f,0.f,0.f};
  const ushort_t* Bl = Bm + half * 64 * 512 + l * 8;

  auto tilef = [&](int tcl, const bf16x8& bfr) {
    f32x4 d4 = __builtin_amdgcn_mfma_f32_16x16x32_bf16(af, bfr, zz, 0, 0, 0);
    const float pv = (MODE != 0) ? spot[(half*64 + tcl)*16 + (l & 15)] : 0.f;
    const float da=fmaxf(d4[0],1e-12f), db=fmaxf(d4[1],1e-12f);
    const float dc=fmaxf(d4[2],1e-12f), dd=fmaxf(d4[3],1e-12f);
    if (CHAM){ d0=fminf(d0,da); d1=fminf(d1,db); d2=fminf(d2,dc); d3=fminf(d3,dd); }
    const float Ca=fsqrt_(da), Cb=fsqrt_(db), Cc=fsqrt_(dc), Cd=fsqrt_(dd);
    float ea,eb,ec,ed;
    if (MODE==0){ ea=-KSCALE*Ca; eb=-KSCALE*Cb; ec=-KSCALE*Cc; ed=-KSCALE*Cd; }
    else if (MODE==1){
      ea=fmaf(-KSCALE,Ca,pv); eb=fmaf(-KSCALE,Cb,pv);
      ec=fmaf(-KSCALE,Cc,pv); ed=fmaf(-KSCALE,Cd,pv);
    } else {
      ea=fmaf(-KSCALE,Ca,pv)+my0; eb=fmaf(-KSCALE,Cb,pv)+my1;
      ec=fmaf(-KSCALE,Cc,pv)+my2; ed=fmaf(-KSCALE,Cd,pv)+my3;
    }
    s0+=fexp2(ea); s1+=fexp2(eb); s2+=fexp2(ec); s3+=fexp2(ed);
  };

  // depth-2 ping-pong prefetch, no barriers
  bf16x8 a0 = *reinterpret_cast<const bf16x8*>(Bl + 0*512);
  bf16x8 a1 = *reinterpret_cast<const bf16x8*>(Bl + 1*512);
  for (int tc = 0; tc < 64; tc += 4) {
    bf16x8 b0 = *reinterpret_cast<const bf16x8*>(Bl + (tc+2)*512);
    bf16x8 b1 = *reinterpret_cast<const bf16x8*>(Bl + (tc+3)*512);
    tilef(tc+0, a0); tilef(tc+1, a1);
    if (tc + 4 < 64) {
      a0 = *reinterpret_cast<const bf16x8*>(Bl + (tc+4)*512);
      a1 = *reinterpret_cast<const bf16x8*>(Bl + (tc+5)*512);
    }
    tilef(tc+2, b0); tilef(tc+3, b1);
  }

  // reduce across the 16 col-lanes of each row
#pragma unroll
  for (int o = 1; o < 16; o <<= 1) {
    s0 += __shfl_xor(s0,o); s1 += __shfl_xor(s1,o);
    s2 += __shfl_xor(s2,o); s3 += __shfl_xor(s3,o);
    if (CHAM){
      d0=fminf(d0,__shfl_xor(d0,o)); d1=fminf(d1,__shfl_xor(d1,o));
      d2=fminf(d2,__shfl_xor(d2,o)); d3=fminf(d3,__shfl_xor(d3,o));
    }
  }
  if ((l & 15) == 0) {
    const int g = l >> 4;
    ssum[w][g*4+0]=s0; ssum[w][g*4+1]=s1; ssum[w][g*4+2]=s2; ssum[w][g*4+3]=s3;
    if (CHAM){ sdm[w][g*4+0]=d0; sdm[w][g*4+1]=d1; sdm[w][g*4+2]=d2; sdm[w][g*4+3]=d3; }
  }
  __syncthreads();
  // combine the two column halves; finalize potentials
  if (w < 4 && l < 16) {
    const int grow = rowbase + w*16 + l;
    const float S = ssum[w][l] + ssum[w+4][l];
    const float shift = (MODE==2) ? pout[grow] : 0.f;   // old value, pre-overwrite
    pout[grow] = shift - 11.0f - flog2(S);
  }
  if (CHAM) {
    if (w < 4) {
      float dmr = (l < 16) ? fminf(sdm[w][l], sdm[w+4][l]) : 0.f;
#pragma unroll
      for (int o = 1; o < 16; o <<= 1) dmr += __shfl_xor(dmr, o);
      if (l == 0) sds[w] = dmr;
    }
    __syncthreads();
    if (tid == 0) atomicAdd(chamf, (sds[0]+sds[1])+(sds[2]+sds[3]));
  }
}

// cost_m = sum_ij 2^(F_i + G_j - K*C_ij) * C_ij
__global__ void __launch_bounds__(512, 8) cost_kernel(
    const ushort_t* __restrict__ Lpred, const ushort_t* __restrict__ Rgt,
    const float* __restrict__ F, const float* __restrict__ G,
    float* __restrict__ cost)
{
  const int bx = blockIdx.x;
  const int m   = bx >> 5;
  const int rg5 = bx & 31;
  const int b   = m >> 1;
  const int tid = threadIdx.x;
  const int l   = tid & 63;
  const int w   = __builtin_amdgcn_readfirstlane(tid >> 6);
  const int wr  = w & 3;
  const int half= w >> 2;

  const ushort_t* A  = Lpred + m*65536;
  const float* pin = G + m*NPTS;
  const float* Fm  = F + m*NPTS;
  const int rowbase = rg5 * 64;
  const int myrow16 = rowbase + wr * 16;

  __shared__ float spot[NPTS];
  __shared__ float sc[8];
  for (int i = tid; i < NPTS; i += 512) spot[i] = pin[i];
  __syncthreads();

  const bf16x8 af = *reinterpret_cast<const bf16x8*>(A + (myrow16 >> 4) * 512 + l * 8);
  const int rg = myrow16 + ((l >> 4) << 2);
  const float F0=Fm[rg+0], F1=Fm[rg+1], F2=Fm[rg+2], F3=Fm[rg+3];
  float c0=0.f,c1=0.f,c2=0.f,c3=0.f;
  const f32x4 zz = {0.f,0.f,0.f,0.f};
  const ushort_t* Bl = Rgt + b*65536 + half * 64 * 512 + l * 8;

  auto tilef = [&](int tcl, const bf16x8& bfr) {
    f32x4 d4 = __builtin_amdgcn_mfma_f32_16x16x32_bf16(af, bfr, zz, 0, 0, 0);
    const float pv = spot[(half*64 + tcl)*16 + (l & 15)];
    const float da=fmaxf(d4[0],1e-12f), db=fmaxf(d4[1],1e-12f);
    const float dc=fmaxf(d4[2],1e-12f), dd=fmaxf(d4[3],1e-12f);
    const float Ca=fsqrt_(da), Cb=fsqrt_(db), Cc=fsqrt_(dc), Cd=fsqrt_(dd);
    c0 = fmaf(fexp2(fmaf(-KSCALE,Ca,pv)+F0), Ca, c0);
    c1 = fmaf(fexp2(fmaf(-KSCALE,Cb,pv)+F1), Cb, c1);
    c2 = fmaf(fexp2(fmaf(-KSCALE,Cc,pv)+F2), Cc, c2);
    c3 = fmaf(fexp2(fmaf(-KSCALE,Cd,pv)+F3), Cd, c3);
  };

  bf16x8 a0 = *reinterpret_cast<const bf16x8*>(Bl + 0*512);
  bf16x8 a1 = *reinterpret_cast<const bf16x8*>(Bl + 1*512);
  for (int tc = 0; tc < 64; tc += 4) {
    bf16x8 b0 = *reinterpret_cast<const bf16x8*>(Bl + (tc+2)*512);
    bf16x8 b1 = *reinterpret_cast<const bf16x8*>(Bl + (tc+3)*512);
    tilef(tc+0, a0); tilef(tc+1, a1);
    if (tc + 4 < 64) {
      a0 = *reinterpret_cast<const bf16x8*>(Bl + (tc+4)*512);
      a1 = *reinterpret_cast<const bf16x8*>(Bl + (tc+5)*512);
    }
    tilef(tc+2, b0); tilef(tc+3, b1);
  }

  float c = (c0+c1)+(c2+c3);
#pragma unroll
  for (int o = 1; o < 64; o <<= 1) c += __shfl_xor(c,o);
  if (l == 0) sc[w] = c;
  __syncthreads();
  if (tid == 0) {
    float t = 0.f;
#pragma unroll
    for (int q = 0; q < 8; ++q) t += sc[q];
    atomicAdd(&cost[m], t);
  }
}

__global__ void final_kernel(const float* __restrict__ cost,
                             const float* __restrict__ chamf,
                             float* __restrict__ out)
{
  if (blockIdx.x == 0 && threadIdx.x == 0) {
    float cs = 0.f;
    for (int i = 0; i < NMAT; ++i) cs += cost[i];
    out[0] = chamf[0] / (float)(BATCH * NPTS) + cs / (float)BATCH;
  }
}

extern "C" void kernel_launch(void* const* d_in, const int* in_sizes, int n_in,
                              void* d_out, int out_size, void* d_ws, size_t ws_size,
                              hipStream_t stream) {
  (void)in_sizes; (void)n_in; (void)out_size; (void)ws_size;
  const float* gt = (const float*)d_in[0];
  const float* p0 = (const float*)d_in[2];
  const float* p1 = (const float*)d_in[3];

  ushort_t* Lpred = (ushort_t*)d_ws;                  // 4MB
  ushort_t* Rpred = Lpred + NMAT * 65536;             // 4MB
  ushort_t* Lgt   = Rpred + NMAT * 65536;             // 2MB
  ushort_t* Rgt   = Lgt + BATCH * 65536;              // 2MB
  float* F     = (float*)(Rgt + BATCH * 65536);
  float* G     = F + NMAT * NPTS;
  float* cost  = G + NMAT * NPTS;
  float* chamf = cost + NMAT;

  const int initN = (NMAT + BATCH) * NPTS + NMAT + 1;
  pack_kernel<<<(initN + 255) / 256, 256, 0, stream>>>(gt, p0, p1, Lpred, Rpred, Lgt, Rgt, cost, chamf);

  const int grid = NMAT * 32;   // 1024 blocks, 8 waves each, 64 rows/block
  sink_kernel<1, 0, 0><<<grid, 512, 0, stream>>>(Lpred, Rpred, Lgt, Rgt, F, G, chamf);
  sink_kernel<1, 1, 1><<<grid, 512, 0, stream>>>(Lpred, Rpred, Lgt, Rgt, F, G, chamf);
  for (int it = 1; it < ITERS; ++it) {
    sink_kernel<0, 2, 0><<<grid, 512, 0, stream>>>(Lpred, Rpred, Lgt, Rgt, F, G, chamf);
    sink_kernel<0, 2, 1><<<grid, 512, 0, stream>>>(Lpred, Rpred, Lgt, Rgt, F, G, chamf);
  }
  cost_kernel<<<grid, 512, 0, stream>>>(Lpred, Rgt, F, G, cost);
  final_kernel<<<1, 64, 0, stream>>>(cost, chamf, (float*)d_out);
}

// Round 7
// 1436.188 us; speedup vs baseline: 1.8658x; 1.0573x over previous
//
#include <hip/hip_runtime.h>

#define BATCH 16
#define NPTS  2048
#define NMAT  32   // 16 batches x 2 preds
#define ITERS 20

typedef short bf16x8 __attribute__((ext_vector_type(8)));
typedef float f32x4 __attribute__((ext_vector_type(4)));
typedef unsigned short ushort_t;
typedef unsigned int uint_t;

// K = log2(e)/EPS, EPS = 0.05. Potentials pre-scaled: F = f*K.
// No LSE shift needed: terms 2^(pv - K*C) stay within fp32 range by ~80 bits
// for |pot| < ~90 (empirically |pot| < ~35 on these inputs).
constexpr float KSCALE = 28.853900817779268f;

__device__ __forceinline__ float fexp2(float x){ return __builtin_amdgcn_exp2f(x); }
__device__ __forceinline__ float flog2(float x){ return __builtin_amdgcn_logf(x); }
__device__ __forceinline__ float fsqrt_(float x){ return __builtin_amdgcn_sqrtf(x); }

__device__ __forceinline__ ushort_t bfr16(float x){
  uint_t u = __float_as_uint(x);
  return (ushort_t)((u + 0x7FFFu + ((u >> 16) & 1u)) >> 16);
}
__device__ __forceinline__ float bfrf(float x){
  return __uint_as_float(((uint_t)bfr16(x)) << 16);
}

// Per-point MFMA fragment encodings (27 used slots of K=32), bf16:
// per component c: L=[nh,nm,nl, 1,1,1, -2ah,-2ah,-2al], R=[1,1,1, nh,nm,nl, bh,bl,bh]
// sum_k L_k(p)*R_k(g) = |p|^2 + |g|^2 - 2(ah*bh+ah*bl+al*bh) ~= ||p-g||^2.
// Storage per cloud: 128 tiles x 1KB; lane l of tile t reads 16B at t*1024+l*16
// holding point (l&15)'s slots (l>>4)*8..+7 (A and B identical layout).
__device__ __forceinline__ void store_enc(ushort_t* base, int pt, const ushort_t* enc){
  ushort_t* p = base + (pt >> 4) * 512 + (pt & 15) * 8;
#pragma unroll
  for (int g = 0; g < 4; ++g){
    *reinterpret_cast<ushort4*>(p + g*128)     = make_ushort4(enc[g*8+0],enc[g*8+1],enc[g*8+2],enc[g*8+3]);
    *reinterpret_cast<ushort4*>(p + g*128 + 4) = make_ushort4(enc[g*8+4],enc[g*8+5],enc[g*8+6],enc[g*8+7]);
  }
}

__global__ void __launch_bounds__(256) pack_kernel(
    const float* __restrict__ gt, const float* __restrict__ p0, const float* __restrict__ p1,
    ushort_t* __restrict__ Lpred, ushort_t* __restrict__ Rpred,
    ushort_t* __restrict__ Lgt,   ushort_t* __restrict__ Rgt,
    float* __restrict__ cost, float* __restrict__ chamf)
{
  const int idx = blockIdx.x * 256 + threadIdx.x;
  const int totalPts = (NMAT + BATCH) * NPTS;
  if (idx < totalPts) {
    const int cl = idx >> 11, pt = idx & (NPTS - 1);
    const float* src; ushort_t *Lb, *Rb;
    if (cl < NMAT) {
      const int b = cl >> 1;
      src = ((cl & 1) ? p1 : p0) + (b * NPTS + pt) * 3;
      Lb = Lpred + cl * 65536; Rb = Rpred + cl * 65536;
    } else {
      const int b = cl - NMAT;
      src = gt + (b * NPTS + pt) * 3;
      Lb = Lgt + b * 65536; Rb = Rgt + b * 65536;
    }
    float L[32], R[32];
#pragma unroll
    for (int k = 27; k < 32; ++k){ L[k] = 0.f; R[k] = 0.f; }
#pragma unroll
    for (int c = 0; c < 3; ++c){
      const float v  = src[c];
      const float ah = bfrf(v), al = bfrf(v - ah);
      const float n2 = v * v;
      const float nh = bfrf(n2); const float r1 = n2 - nh;
      const float nm = bfrf(r1); const float nl = bfrf(r1 - nm);
      const int B0 = c * 9;
      L[B0+0]=nh;  L[B0+1]=nm;  L[B0+2]=nl;
      L[B0+3]=1.f; L[B0+4]=1.f; L[B0+5]=1.f;
      L[B0+6]=-2.f*ah; L[B0+7]=-2.f*ah; L[B0+8]=-2.f*al;
      R[B0+0]=1.f; R[B0+1]=1.f; R[B0+2]=1.f;
      R[B0+3]=nh;  R[B0+4]=nm;  R[B0+5]=nl;
      R[B0+6]=ah;  R[B0+7]=al;  R[B0+8]=ah;
    }
    ushort_t Le[32], Re[32];
#pragma unroll
    for (int k = 0; k < 32; ++k){ Le[k] = bfr16(L[k]); Re[k] = bfr16(R[k]); }
    store_enc(Lb, pt, Le);
    store_enc(Rb, pt, Re);
  } else if (idx < totalPts + NMAT) {
    cost[idx - totalPts] = 0.f;
  } else if (idx == totalPts + NMAT) {
    chamf[0] = 0.f;
  }
}

// One Sinkhorn half-update over all 32 matrices via MFMA distance tiles.
// Grid = NMAT*32; block = 512 thr = 8 waves = 4 row-waves x 2 col-halves.
// Column potentials read from a TRANSPOSED global array (potT[c*128+t]) with
// one float4 per 4-tile group, prefetched - no LDS staging, no entry barrier.
// Each sink writes its output potential in both layouts (pout + poutT).
// GSIDE=0: rows=pred (writes F/FT); GSIDE=1: rows=gt (writes G/GT).
// RPOT=0: potentials are zero (very first half-update only).
template<int CHAM, int RPOT, int GSIDE>
__global__ void __launch_bounds__(512, 8) sink_kernel(
    const ushort_t* __restrict__ Lpred, const ushort_t* __restrict__ Rpred,
    const ushort_t* __restrict__ Lgt,   const ushort_t* __restrict__ Rgt,
    float* __restrict__ F, float* __restrict__ G,
    float* __restrict__ FT, float* __restrict__ GT,
    float* __restrict__ chamf)
{
  const int bx = blockIdx.x;
  const int m   = bx >> 5;
  const int rg5 = bx & 31;
  const int b   = m >> 1;
  const int tid = threadIdx.x;
  const int l   = tid & 63;
  const int w   = __builtin_amdgcn_readfirstlane(tid >> 6);
  const int wr  = w & 3;
  const int half= w >> 2;

  const ushort_t* A  = GSIDE ? (Lgt + b*65536)   : (Lpred + m*65536);
  const ushort_t* Bm = GSIDE ? (Rpred + m*65536) : (Rgt + b*65536);
  const float* pinT  = (GSIDE ? FT : GT) + m*NPTS;  // transposed col potentials
  float*       pout  = (GSIDE ? G : F) + m*NPTS;
  float*       poutT = (GSIDE ? GT : FT) + m*NPTS;

  const int rowbase = rg5 * 64;
  const int myrow16 = rowbase + wr * 16;

  __shared__ float ssum[8][16];
  __shared__ float sdm[8][16];
  __shared__ float sds[4];

  const bf16x8 af = *reinterpret_cast<const bf16x8*>(A + (myrow16 >> 4) * 512 + l * 8);

  float s0=0.f,s1=0.f,s2=0.f,s3=0.f;
  float d0=1e30f,d1=1e30f,d2=1e30f,d3=1e30f;
  const f32x4 zz = {0.f,0.f,0.f,0.f};
  const ushort_t* Bl = Bm + half * 64 * 512 + l * 8;
  const float*    PT = pinT + (l & 15) * 128 + half * 64;

  auto tilef = [&](const bf16x8& bfr, float pv) {
    f32x4 d4 = __builtin_amdgcn_mfma_f32_16x16x32_bf16(af, bfr, zz, 0, 0, 0);
    const float da=fmaxf(d4[0],1e-12f), db=fmaxf(d4[1],1e-12f);
    const float dc=fmaxf(d4[2],1e-12f), dd=fmaxf(d4[3],1e-12f);
    if (CHAM){ d0=fminf(d0,da); d1=fminf(d1,db); d2=fminf(d2,dc); d3=fminf(d3,dd); }
    const float Ca=fsqrt_(da), Cb=fsqrt_(db), Cc=fsqrt_(dc), Cd=fsqrt_(dd);
    float ea,eb,ec,ed;
    if (RPOT){
      ea=fmaf(-KSCALE,Ca,pv); eb=fmaf(-KSCALE,Cb,pv);
      ec=fmaf(-KSCALE,Cc,pv); ed=fmaf(-KSCALE,Cd,pv);
    } else {
      ea=-KSCALE*Ca; eb=-KSCALE*Cb; ec=-KSCALE*Cc; ed=-KSCALE*Cd;
    }
    s0+=fexp2(ea); s1+=fexp2(eb); s2+=fexp2(ec); s3+=fexp2(ed);
  };

  // depth-1-group staggered prefetch (B frags 2 at a time + 1 float4 of potT)
  bf16x8 c0 = *reinterpret_cast<const bf16x8*>(Bl + 0*512);
  bf16x8 c1 = *reinterpret_cast<const bf16x8*>(Bl + 1*512);
  bf16x8 c2 = *reinterpret_cast<const bf16x8*>(Bl + 2*512);
  bf16x8 c3 = *reinterpret_cast<const bf16x8*>(Bl + 3*512);
  float4 cp = RPOT ? *reinterpret_cast<const float4*>(PT) : make_float4(0.f,0.f,0.f,0.f);
  for (int g = 0; g < 16; ++g) {
    bf16x8 n0, n1, n2, n3; float4 np;
    const ushort_t* nb = Bl + (g*4 + 4) * 512;
    if (g < 15) {
      n0 = *reinterpret_cast<const bf16x8*>(nb);
      n1 = *reinterpret_cast<const bf16x8*>(nb + 512);
      np = RPOT ? *reinterpret_cast<const float4*>(PT + 4*(g+1)) : make_float4(0.f,0.f,0.f,0.f);
    } else { n0=c0; n1=c1; np=cp; }
    tilef(c0, cp.x); tilef(c1, cp.y);
    if (g < 15) {
      n2 = *reinterpret_cast<const bf16x8*>(nb + 1024);
      n3 = *reinterpret_cast<const bf16x8*>(nb + 1536);
    } else { n2=c2; n3=c3; }
    tilef(c2, cp.z); tilef(c3, cp.w);
    c0=n0; c1=n1; c2=n2; c3=n3; cp=np;
  }

  // reduce across the 16 col-lanes of each row
#pragma unroll
  for (int o = 1; o < 16; o <<= 1) {
    s0 += __shfl_xor(s0,o); s1 += __shfl_xor(s1,o);
    s2 += __shfl_xor(s2,o); s3 += __shfl_xor(s3,o);
    if (CHAM){
      d0=fminf(d0,__shfl_xor(d0,o)); d1=fminf(d1,__shfl_xor(d1,o));
      d2=fminf(d2,__shfl_xor(d2,o)); d3=fminf(d3,__shfl_xor(d3,o));
    }
  }
  if ((l & 15) == 0) {
    const int g = l >> 4;
    ssum[w][g*4+0]=s0; ssum[w][g*4+1]=s1; ssum[w][g*4+2]=s2; ssum[w][g*4+3]=s3;
    if (CHAM){ sdm[w][g*4+0]=d0; sdm[w][g*4+1]=d1; sdm[w][g*4+2]=d2; sdm[w][g*4+3]=d3; }
  }
  __syncthreads();
  if (w < 4 && l < 16) {
    const int grow = rowbase + w*16 + l;
    const float S = ssum[w][l] + ssum[w+4][l];
    const float val = -11.0f - flog2(S);
    pout[grow] = val;
    poutT[(grow & 15)*128 + (grow >> 4)] = val;
  }
  if (CHAM) {
    if (w < 4) {
      float dmr = (l < 16) ? fminf(sdm[w][l], sdm[w+4][l]) : 0.f;
#pragma unroll
      for (int o = 1; o < 16; o <<= 1) dmr += __shfl_xor(dmr, o);
      if (l == 0) sds[w] = dmr;
    }
    __syncthreads();
    if (tid == 0) atomicAdd(chamf, (sds[0]+sds[1])+(sds[2]+sds[3]));
  }
}

// cost_m = sum_ij 2^(F_i + G_j - K*C_ij) * C_ij
__global__ void __launch_bounds__(512, 8) cost_kernel(
    const ushort_t* __restrict__ Lpred, const ushort_t* __restrict__ Rgt,
    const float* __restrict__ F, const float* __restrict__ GT,
    float* __restrict__ cost)
{
  const int bx = blockIdx.x;
  const int m   = bx >> 5;
  const int rg5 = bx & 31;
  const int b   = m >> 1;
  const int tid = threadIdx.x;
  const int l   = tid & 63;
  const int w   = __builtin_amdgcn_readfirstlane(tid >> 6);
  const int wr  = w & 3;
  const int half= w >> 2;

  const ushort_t* A  = Lpred + m*65536;
  const float* pinT  = GT + m*NPTS;
  const float* Fm    = F + m*NPTS;
  const int rowbase = rg5 * 64;
  const int myrow16 = rowbase + wr * 16;

  __shared__ float sc[8];

  const bf16x8 af = *reinterpret_cast<const bf16x8*>(A + (myrow16 >> 4) * 512 + l * 8);
  const int rg = myrow16 + ((l >> 4) << 2);
  const float4 Fv = *reinterpret_cast<const float4*>(Fm + rg);
  float c0a=0.f,c1a=0.f,c2a=0.f,c3a=0.f;
  const f32x4 zz = {0.f,0.f,0.f,0.f};
  const ushort_t* Bl = Rgt + b*65536 + half * 64 * 512 + l * 8;
  const float*    PT = pinT + (l & 15) * 128 + half * 64;

  auto tilef = [&](const bf16x8& bfr, float pv) {
    f32x4 d4 = __builtin_amdgcn_mfma_f32_16x16x32_bf16(af, bfr, zz, 0, 0, 0);
    const float da=fmaxf(d4[0],1e-12f), db=fmaxf(d4[1],1e-12f);
    const float dc=fmaxf(d4[2],1e-12f), dd=fmaxf(d4[3],1e-12f);
    const float Ca=fsqrt_(da), Cb=fsqrt_(db), Cc=fsqrt_(dc), Cd=fsqrt_(dd);
    c0a = fmaf(fexp2(fmaf(-KSCALE,Ca,pv)+Fv.x), Ca, c0a);
    c1a = fmaf(fexp2(fmaf(-KSCALE,Cb,pv)+Fv.y), Cb, c1a);
    c2a = fmaf(fexp2(fmaf(-KSCALE,Cc,pv)+Fv.z), Cc, c2a);
    c3a = fmaf(fexp2(fmaf(-KSCALE,Cd,pv)+Fv.w), Cd, c3a);
  };

  bf16x8 c0 = *reinterpret_cast<const bf16x8*>(Bl + 0*512);
  bf16x8 c1 = *reinterpret_cast<const bf16x8*>(Bl + 1*512);
  bf16x8 c2 = *reinterpret_cast<const bf16x8*>(Bl + 2*512);
  bf16x8 c3 = *reinterpret_cast<const bf16x8*>(Bl + 3*512);
  float4 cp = *reinterpret_cast<const float4*>(PT);
  for (int g = 0; g < 16; ++g) {
    bf16x8 n0, n1, n2, n3; float4 np;
    const ushort_t* nb = Bl + (g*4 + 4) * 512;
    if (g < 15) {
      n0 = *reinterpret_cast<const bf16x8*>(nb);
      n1 = *reinterpret_cast<const bf16x8*>(nb + 512);
      np = *reinterpret_cast<const float4*>(PT + 4*(g+1));
    } else { n0=c0; n1=c1; np=cp; }
    tilef(c0, cp.x); tilef(c1, cp.y);
    if (g < 15) {
      n2 = *reinterpret_cast<const bf16x8*>(nb + 1024);
      n3 = *reinterpret_cast<const bf16x8*>(nb + 1536);
    } else { n2=c2; n3=c3; }
    tilef(c2, cp.z); tilef(c3, cp.w);
    c0=n0; c1=n1; c2=n2; c3=n3; cp=np;
  }

  float c = (c0a+c1a)+(c2a+c3a);
#pragma unroll
  for (int o = 1; o < 64; o <<= 1) c += __shfl_xor(c,o);
  if (l == 0) sc[w] = c;
  __syncthreads();
  if (tid == 0) {
    float t = 0.f;
#pragma unroll
    for (int q = 0; q < 8; ++q) t += sc[q];
    atomicAdd(&cost[m], t);
  }
}

__global__ void final_kernel(const float* __restrict__ cost,
                             const float* __restrict__ chamf,
                             float* __restrict__ out)
{
  if (blockIdx.x == 0 && threadIdx.x == 0) {
    float cs = 0.f;
    for (int i = 0; i < NMAT; ++i) cs += cost[i];
    out[0] = chamf[0] / (float)(BATCH * NPTS) + cs / (float)BATCH;
  }
}

extern "C" void kernel_launch(void* const* d_in, const int* in_sizes, int n_in,
                              void* d_out, int out_size, void* d_ws, size_t ws_size,
                              hipStream_t stream) {
  (void)in_sizes; (void)n_in; (void)out_size; (void)ws_size;
  const float* gt = (const float*)d_in[0];
  const float* p0 = (const float*)d_in[2];
  const float* p1 = (const float*)d_in[3];

  ushort_t* Lpred = (ushort_t*)d_ws;                  // 4MB
  ushort_t* Rpred = Lpred + NMAT * 65536;             // 4MB
  ushort_t* Lgt   = Rpred + NMAT * 65536;             // 2MB
  ushort_t* Rgt   = Lgt + BATCH * 65536;              // 2MB
  float* F     = (float*)(Rgt + BATCH * 65536);       // 32*2048
  float* G     = F + NMAT * NPTS;                     // 32*2048
  float* FT    = G + NMAT * NPTS;                     // 32*2048 (transposed)
  float* GT    = FT + NMAT * NPTS;                    // 32*2048 (transposed)
  float* cost  = GT + NMAT * NPTS;                    // 32
  float* chamf = cost + NMAT;                         // 1

  const int initN = (NMAT + BATCH) * NPTS + NMAT + 1;
  pack_kernel<<<(initN + 255) / 256, 256, 0, stream>>>(gt, p0, p1, Lpred, Rpred, Lgt, Rgt, cost, chamf);

  const int grid = NMAT * 32;   // 1024 blocks, 8 waves each, 64 rows/block
  sink_kernel<1, 0, 0><<<grid, 512, 0, stream>>>(Lpred, Rpred, Lgt, Rgt, F, G, FT, GT, chamf);
  sink_kernel<1, 1, 1><<<grid, 512, 0, stream>>>(Lpred, Rpred, Lgt, Rgt, F, G, FT, GT, chamf);
  for (int it = 1; it < ITERS; ++it) {
    sink_kernel<0, 1, 0><<<grid, 512, 0, stream>>>(Lpred, Rpred, Lgt, Rgt, F, G, FT, GT, chamf);
    sink_kernel<0, 1, 1><<<grid, 512, 0, stream>>>(Lpred, Rpred, Lgt, Rgt, F, G, FT, GT, chamf);
  }
  cost_kernel<<<grid, 512, 0, stream>>>(Lpred, Rgt, F, GT, cost);
  final_kernel<<<1, 64, 0, stream>>>(cost, chamf, (float*)d_out);
}

// Round 8
// 1374.861 us; speedup vs baseline: 1.9491x; 1.0446x over previous
//
#include <hip/hip_runtime.h>

#define BATCH 16
#define NPTS  2048
#define NMAT  32   // 16 batches x 2 preds
#define ITERS 20

typedef short bf16x8 __attribute__((ext_vector_type(8)));
typedef float f32x4 __attribute__((ext_vector_type(4)));
typedef unsigned short ushort_t;
typedef unsigned int uint_t;

// K = log2(e)/EPS, EPS = 0.05. Potentials pre-scaled: F = f*K (log2-domain).
// No LSE shift needed: terms 2^(pv - K*C) stay in fp32 range by ~80 bits.
constexpr float KSCALE = 28.853900817779268f;

__device__ __forceinline__ float fexp2(float x){ return __builtin_amdgcn_exp2f(x); }
__device__ __forceinline__ float flog2(float x){ return __builtin_amdgcn_logf(x); }
__device__ __forceinline__ float fsqrt_(float x){ return __builtin_amdgcn_sqrtf(x); }

__device__ __forceinline__ ushort_t bfr16(float x){
  uint_t u = __float_as_uint(x);
  return (ushort_t)((u + 0x7FFFu + ((u >> 16) & 1u)) >> 16);
}
__device__ __forceinline__ float bfrf(float x){
  return __uint_as_float(((uint_t)bfr16(x)) << 16);
}

// Per-point MFMA fragment encodings (27 used slots of K=32), bf16:
// per component c: L=[nh,nm,nl, 1,1,1, -2ah,-2ah,-2al], R=[1,1,1, nh,nm,nl, bh,bl,bh]
// sum_k L_k(p)*R_k(g) = |p|^2 + |g|^2 - 2(ah*bh+ah*bl+al*bh) ~= ||p-g||^2.
// Storage per cloud: 128 tiles x 1KB; lane l of tile t reads 16B at t*1024+l*16
// holding point (l&15)'s slots (l>>4)*8..+7 (A and B identical layout).
__device__ __forceinline__ void store_enc(ushort_t* base, int pt, const ushort_t* enc){
  ushort_t* p = base + (pt >> 4) * 512 + (pt & 15) * 8;
#pragma unroll
  for (int g = 0; g < 4; ++g){
    *reinterpret_cast<ushort4*>(p + g*128)     = make_ushort4(enc[g*8+0],enc[g*8+1],enc[g*8+2],enc[g*8+3]);
    *reinterpret_cast<ushort4*>(p + g*128 + 4) = make_ushort4(enc[g*8+4],enc[g*8+5],enc[g*8+6],enc[g*8+7]);
  }
}

__global__ void __launch_bounds__(256) pack_kernel(
    const float* __restrict__ gt, const float* __restrict__ p0, const float* __restrict__ p1,
    ushort_t* __restrict__ Lpred, ushort_t* __restrict__ Rpred,
    ushort_t* __restrict__ Lgt,   ushort_t* __restrict__ Rgt,
    float* __restrict__ emd, float* __restrict__ chamf)
{
  const int idx = blockIdx.x * 256 + threadIdx.x;
  const int totalPts = (NMAT + BATCH) * NPTS;
  if (idx < totalPts) {
    const int cl = idx >> 11, pt = idx & (NPTS - 1);
    const float* src; ushort_t *Lb, *Rb;
    if (cl < NMAT) {
      const int b = cl >> 1;
      src = ((cl & 1) ? p1 : p0) + (b * NPTS + pt) * 3;
      Lb = Lpred + cl * 65536; Rb = Rpred + cl * 65536;
    } else {
      const int b = cl - NMAT;
      src = gt + (b * NPTS + pt) * 3;
      Lb = Lgt + b * 65536; Rb = Rgt + b * 65536;
    }
    float L[32], R[32];
#pragma unroll
    for (int k = 27; k < 32; ++k){ L[k] = 0.f; R[k] = 0.f; }
#pragma unroll
    for (int c = 0; c < 3; ++c){
      const float v  = src[c];
      const float ah = bfrf(v), al = bfrf(v - ah);
      const float n2 = v * v;
      const float nh = bfrf(n2); const float r1 = n2 - nh;
      const float nm = bfrf(r1); const float nl = bfrf(r1 - nm);
      const int B0 = c * 9;
      L[B0+0]=nh;  L[B0+1]=nm;  L[B0+2]=nl;
      L[B0+3]=1.f; L[B0+4]=1.f; L[B0+5]=1.f;
      L[B0+6]=-2.f*ah; L[B0+7]=-2.f*ah; L[B0+8]=-2.f*al;
      R[B0+0]=1.f; R[B0+1]=1.f; R[B0+2]=1.f;
      R[B0+3]=nh;  R[B0+4]=nm;  R[B0+5]=nl;
      R[B0+6]=ah;  R[B0+7]=al;  R[B0+8]=ah;
    }
    ushort_t Le[32], Re[32];
#pragma unroll
    for (int k = 0; k < 32; ++k){ Le[k] = bfr16(L[k]); Re[k] = bfr16(R[k]); }
    store_enc(Lb, pt, Le);
    store_enc(Rb, pt, Re);
  } else if (idx == totalPts) {
    emd[0] = 0.f;
  } else if (idx == totalPts + 1) {
    chamf[0] = 0.f;
  }
}

// One Sinkhorn half-update over all 32 matrices via MFMA distance tiles.
// Grid = NMAT*32; block = 512 thr = 8 waves = 4 row-waves x 2 col-halves.
// Potentials live ONLY in transposed layout: potT[(i&15)*128 + (i>>4)],
// so lane l fetches its 4-tile group's col-potentials as one float4.
// GSIDE=0: rows=pred (writes FT); GSIDE=1: rows=gt (writes GT).
// RPOT=0: input potentials are zero (very first half-update only).
// COST=1 (final g-update only): also accumulate T_j = sum_i 2^(F_i-K*C)*C,
// then emd += sum_j 2^(G_j) * T_j  (cost fused, no separate pass needed).
template<int CHAM, int RPOT, int GSIDE, int COST>
__global__ void __launch_bounds__(512, 8) sink_kernel(
    const ushort_t* __restrict__ Lpred, const ushort_t* __restrict__ Rpred,
    const ushort_t* __restrict__ Lgt,   const ushort_t* __restrict__ Rgt,
    float* __restrict__ FT, float* __restrict__ GT,
    float* __restrict__ chamf, float* __restrict__ emd)
{
  const int bx = blockIdx.x;
  const int m   = bx >> 5;
  const int rg5 = bx & 31;
  const int b   = m >> 1;
  const int tid = threadIdx.x;
  const int l   = tid & 63;
  const int w   = __builtin_amdgcn_readfirstlane(tid >> 6);
  const int wr  = w & 3;
  const int half= w >> 2;

  const ushort_t* A  = GSIDE ? (Lgt + b*65536)   : (Lpred + m*65536);
  const ushort_t* Bm = GSIDE ? (Rpred + m*65536) : (Rgt + b*65536);
  const float* pinT  = (GSIDE ? FT : GT) + m*NPTS;
  float*       poutT = (GSIDE ? GT : FT) + m*NPTS;

  const int rowbase = rg5 * 64;
  const int myrow16 = rowbase + wr * 16;

  __shared__ float ssum[8][16];
  __shared__ float sdm[8][16];   // chamfer mins OR cost T sums (never both)
  __shared__ float sds[4];

  const bf16x8 af = *reinterpret_cast<const bf16x8*>(A + (myrow16 >> 4) * 512 + l * 8);

  float s0=0.f,s1=0.f,s2=0.f,s3=0.f;
  float d0=1e30f,d1=1e30f,d2=1e30f,d3=1e30f;
  float t0=0.f,t1=0.f,t2=0.f,t3=0.f;
  const f32x4 zz = {0.f,0.f,0.f,0.f};
  const ushort_t* Bl = Bm + half * 64 * 512 + l * 8;
  const float*    PT = pinT + (l & 15) * 128 + half * 64;

  auto tilef = [&](const bf16x8& bfr, float pv) {
    f32x4 d4 = __builtin_amdgcn_mfma_f32_16x16x32_bf16(af, bfr, zz, 0, 0, 0);
    const float da=fmaxf(d4[0],1e-12f), db=fmaxf(d4[1],1e-12f);
    const float dc=fmaxf(d4[2],1e-12f), dd=fmaxf(d4[3],1e-12f);
    if (CHAM){ d0=fminf(d0,da); d1=fminf(d1,db); d2=fminf(d2,dc); d3=fminf(d3,dd); }
    const float Ca=fsqrt_(da), Cb=fsqrt_(db), Cc=fsqrt_(dc), Cd=fsqrt_(dd);
    float ea,eb,ec,ed;
    if (RPOT){
      ea=fmaf(-KSCALE,Ca,pv); eb=fmaf(-KSCALE,Cb,pv);
      ec=fmaf(-KSCALE,Cc,pv); ed=fmaf(-KSCALE,Cd,pv);
    } else {
      ea=-KSCALE*Ca; eb=-KSCALE*Cb; ec=-KSCALE*Cc; ed=-KSCALE*Cd;
    }
    const float xa=fexp2(ea), xb=fexp2(eb), xc=fexp2(ec), xd=fexp2(ed);
    s0+=xa; s1+=xb; s2+=xc; s3+=xd;
    if (COST){
      t0=fmaf(xa,Ca,t0); t1=fmaf(xb,Cb,t1);
      t2=fmaf(xc,Cc,t2); t3=fmaf(xd,Cd,t3);
    }
  };

  // flat 4-tile-group loop; compiler pipelines the loads (no manual rotation)
#pragma unroll 2
  for (int g4 = 0; g4 < 16; ++g4) {
    float4 cp;
    if (RPOT) cp = *reinterpret_cast<const float4*>(PT + g4*4);
    else      cp = make_float4(0.f,0.f,0.f,0.f);
    tilef(*reinterpret_cast<const bf16x8*>(Bl + (g4*4+0)*512), cp.x);
    tilef(*reinterpret_cast<const bf16x8*>(Bl + (g4*4+1)*512), cp.y);
    tilef(*reinterpret_cast<const bf16x8*>(Bl + (g4*4+2)*512), cp.z);
    tilef(*reinterpret_cast<const bf16x8*>(Bl + (g4*4+3)*512), cp.w);
  }

  // reduce across the 16 col-lanes of each row
#pragma unroll
  for (int o = 1; o < 16; o <<= 1) {
    s0 += __shfl_xor(s0,o); s1 += __shfl_xor(s1,o);
    s2 += __shfl_xor(s2,o); s3 += __shfl_xor(s3,o);
    if (CHAM){
      d0=fminf(d0,__shfl_xor(d0,o)); d1=fminf(d1,__shfl_xor(d1,o));
      d2=fminf(d2,__shfl_xor(d2,o)); d3=fminf(d3,__shfl_xor(d3,o));
    }
    if (COST){
      t0 += __shfl_xor(t0,o); t1 += __shfl_xor(t1,o);
      t2 += __shfl_xor(t2,o); t3 += __shfl_xor(t3,o);
    }
  }
  if ((l & 15) == 0) {
    const int g = l >> 4;
    ssum[w][g*4+0]=s0; ssum[w][g*4+1]=s1; ssum[w][g*4+2]=s2; ssum[w][g*4+3]=s3;
    if (CHAM){ sdm[w][g*4+0]=d0; sdm[w][g*4+1]=d1; sdm[w][g*4+2]=d2; sdm[w][g*4+3]=d3; }
    if (COST){ sdm[w][g*4+0]=t0; sdm[w][g*4+1]=t1; sdm[w][g*4+2]=t2; sdm[w][g*4+3]=t3; }
  }
  __syncthreads();
  float val = 0.f;
  if (w < 4 && l < 16) {
    const int grow = rowbase + w*16 + l;
    const float S = ssum[w][l] + ssum[w+4][l];
    val = -11.0f - flog2(S);
    poutT[(grow & 15)*128 + (grow >> 4)] = val;
  }
  if (CHAM) {
    if (w < 4) {
      float dmr = (l < 16) ? fminf(sdm[w][l], sdm[w+4][l]) : 0.f;
#pragma unroll
      for (int o = 1; o < 16; o <<= 1) dmr += __shfl_xor(dmr, o);
      if (l == 0) sds[w] = dmr;
    }
    __syncthreads();
    if (tid == 0) atomicAdd(chamf, (sds[0]+sds[1])+(sds[2]+sds[3]));
  }
  if (COST) {
    if (w < 4) {
      float cj = (l < 16) ? fexp2(val) * (sdm[w][l] + sdm[w+4][l]) : 0.f;
#pragma unroll
      for (int o = 1; o < 16; o <<= 1) cj += __shfl_xor(cj, o);
      if (l == 0) sds[w] = cj;
    }
    __syncthreads();
    if (tid == 0) atomicAdd(emd, (sds[0]+sds[1])+(sds[2]+sds[3]));
  }
}

__global__ void final_kernel(const float* __restrict__ emd,
                             const float* __restrict__ chamf,
                             float* __restrict__ out)
{
  if (blockIdx.x == 0 && threadIdx.x == 0) {
    out[0] = chamf[0] / (float)(BATCH * NPTS) + emd[0] / (float)BATCH;
  }
}

extern "C" void kernel_launch(void* const* d_in, const int* in_sizes, int n_in,
                              void* d_out, int out_size, void* d_ws, size_t ws_size,
                              hipStream_t stream) {
  (void)in_sizes; (void)n_in; (void)out_size; (void)ws_size;
  const float* gt = (const float*)d_in[0];
  const float* p0 = (const float*)d_in[2];
  const float* p1 = (const float*)d_in[3];

  ushort_t* Lpred = (ushort_t*)d_ws;                  // 4MB
  ushort_t* Rpred = Lpred + NMAT * 65536;             // 4MB
  ushort_t* Lgt   = Rpred + NMAT * 65536;             // 2MB
  ushort_t* Rgt   = Lgt + BATCH * 65536;              // 2MB
  float* FT    = (float*)(Rgt + BATCH * 65536);       // 32*2048 (transposed)
  float* GT    = FT + NMAT * NPTS;                    // 32*2048 (transposed)
  float* emd   = GT + NMAT * NPTS;                    // 1
  float* chamf = emd + 1;                             // 1

  const int initN = (NMAT + BATCH) * NPTS + 2;
  pack_kernel<<<(initN + 255) / 256, 256, 0, stream>>>(gt, p0, p1, Lpred, Rpred, Lgt, Rgt, emd, chamf);

  const int grid = NMAT * 32;   // 1024 blocks, 8 waves each, 64 rows/block
  sink_kernel<1, 0, 0, 0><<<grid, 512, 0, stream>>>(Lpred, Rpred, Lgt, Rgt, FT, GT, chamf, emd);
  sink_kernel<1, 1, 1, 0><<<grid, 512, 0, stream>>>(Lpred, Rpred, Lgt, Rgt, FT, GT, chamf, emd);
  for (int it = 1; it < ITERS - 1; ++it) {
    sink_kernel<0, 1, 0, 0><<<grid, 512, 0, stream>>>(Lpred, Rpred, Lgt, Rgt, FT, GT, chamf, emd);
    sink_kernel<0, 1, 1, 0><<<grid, 512, 0, stream>>>(Lpred, Rpred, Lgt, Rgt, FT, GT, chamf, emd);
  }
  // final iteration: f-update, then g-update with fused EMD cost
  sink_kernel<0, 1, 0, 0><<<grid, 512, 0, stream>>>(Lpred, Rpred, Lgt, Rgt, FT, GT, chamf, emd);
  sink_kernel<0, 1, 1, 1><<<grid, 512, 0, stream>>>(Lpred, Rpred, Lgt, Rgt, FT, GT, chamf, emd);
  final_kernel<<<1, 64, 0, stream>>>(emd, chamf, (float*)d_out);
}

// Round 9
// 1287.244 us; speedup vs baseline: 2.0817x; 1.0681x over previous
//
#include <hip/hip_runtime.h>

#define BATCH 16
#define NPTS  2048
#define NMAT  32   // 16 batches x 2 preds
#define ITERS 20

typedef short bf16x8 __attribute__((ext_vector_type(8)));
typedef float f32x4 __attribute__((ext_vector_type(4)));
typedef unsigned short ushort_t;
typedef unsigned int uint_t;

// K = log2(e)/EPS, EPS = 0.05. Potentials pre-scaled: F = f*K (log2-domain).
// No LSE shift needed: terms 2^(pv - K*C) stay in fp32 range by ~80 bits.
constexpr float KSCALE = 28.853900817779268f;

__device__ __forceinline__ float fexp2(float x){ return __builtin_amdgcn_exp2f(x); }
__device__ __forceinline__ float flog2(float x){ return __builtin_amdgcn_logf(x); }
__device__ __forceinline__ float fsqrt_(float x){ return __builtin_amdgcn_sqrtf(x); }

__device__ __forceinline__ ushort_t bfr16(float x){
  uint_t u = __float_as_uint(x);
  return (ushort_t)((u + 0x7FFFu + ((u >> 16) & 1u)) >> 16);
}
__device__ __forceinline__ float bfrf(float x){
  return __uint_as_float(((uint_t)bfr16(x)) << 16);
}

// Per-point MFMA fragment encodings (27 used slots of K=32), bf16:
// per component c: L=[nh,nm,nl, 1,1,1, -2ah,-2ah,-2al], R=[1,1,1, nh,nm,nl, bh,bl,bh]
// sum_k L_k(p)*R_k(g) = |p|^2 + |g|^2 - 2(ah*bh+ah*bl+al*bh) ~= ||p-g||^2.
// Storage per cloud: 128 tiles x 1KB; lane l of tile t reads 16B at t*1024+l*16
// holding point (l&15)'s slots (l>>4)*8..+7 (A and B identical layout).
__device__ __forceinline__ void store_enc(ushort_t* base, int pt, const ushort_t* enc){
  ushort_t* p = base + (pt >> 4) * 512 + (pt & 15) * 8;
#pragma unroll
  for (int g = 0; g < 4; ++g){
    *reinterpret_cast<ushort4*>(p + g*128)     = make_ushort4(enc[g*8+0],enc[g*8+1],enc[g*8+2],enc[g*8+3]);
    *reinterpret_cast<ushort4*>(p + g*128 + 4) = make_ushort4(enc[g*8+4],enc[g*8+5],enc[g*8+6],enc[g*8+7]);
  }
}

__global__ void __launch_bounds__(256) pack_kernel(
    const float* __restrict__ gt, const float* __restrict__ p0, const float* __restrict__ p1,
    ushort_t* __restrict__ Lpred, ushort_t* __restrict__ Rpred,
    ushort_t* __restrict__ Lgt,   ushort_t* __restrict__ Rgt,
    float* __restrict__ emd, float* __restrict__ chamf)
{
  const int idx = blockIdx.x * 256 + threadIdx.x;
  const int totalPts = (NMAT + BATCH) * NPTS;
  if (idx < totalPts) {
    const int cl = idx >> 11, pt = idx & (NPTS - 1);
    const float* src; ushort_t *Lb, *Rb;
    if (cl < NMAT) {
      const int b = cl >> 1;
      src = ((cl & 1) ? p1 : p0) + (b * NPTS + pt) * 3;
      Lb = Lpred + cl * 65536; Rb = Rpred + cl * 65536;
    } else {
      const int b = cl - NMAT;
      src = gt + (b * NPTS + pt) * 3;
      Lb = Lgt + b * 65536; Rb = Rgt + b * 65536;
    }
    float L[32], R[32];
#pragma unroll
    for (int k = 27; k < 32; ++k){ L[k] = 0.f; R[k] = 0.f; }
#pragma unroll
    for (int c = 0; c < 3; ++c){
      const float v  = src[c];
      const float ah = bfrf(v), al = bfrf(v - ah);
      const float n2 = v * v;
      const float nh = bfrf(n2); const float r1 = n2 - nh;
      const float nm = bfrf(r1); const float nl = bfrf(r1 - nm);
      const int B0 = c * 9;
      L[B0+0]=nh;  L[B0+1]=nm;  L[B0+2]=nl;
      L[B0+3]=1.f; L[B0+4]=1.f; L[B0+5]=1.f;
      L[B0+6]=-2.f*ah; L[B0+7]=-2.f*ah; L[B0+8]=-2.f*al;
      R[B0+0]=1.f; R[B0+1]=1.f; R[B0+2]=1.f;
      R[B0+3]=nh;  R[B0+4]=nm;  R[B0+5]=nl;
      R[B0+6]=ah;  R[B0+7]=al;  R[B0+8]=ah;
    }
    ushort_t Le[32], Re[32];
#pragma unroll
    for (int k = 0; k < 32; ++k){ Le[k] = bfr16(L[k]); Re[k] = bfr16(R[k]); }
    store_enc(Lb, pt, Le);
    store_enc(Rb, pt, Re);
  } else if (idx == totalPts) {
    emd[0] = 0.f;
  } else if (idx == totalPts + 1) {
    chamf[0] = 0.f;
  }
}

// One Sinkhorn half-update over all 32 matrices via MFMA distance tiles.
// Grid = NMAT*32 (XCD-swizzled); block = 512 thr = 8 waves = 4 row-waves x 2 halves.
// Potentials in group-of-4 layout: pot[(t>>2)*64 + c*4 + (t&3)] for point
// index i = t*16+c. Readers: lane l loads one float4 (4 tiles' pv for its col)
// from a contiguous 1KB chunk per group; writers: one dense 256B per block.
// GSIDE=0: rows=pred (writes FT); GSIDE=1: rows=gt (writes GT).
// RPOT=0: input potentials are zero (very first half-update only).
// COST=1 (final g-update only): also accumulate T_j = sum_i 2^(F_i-K*C)*C,
// then emd += sum_j 2^(G_j) * T_j  (cost fused).
template<int CHAM, int RPOT, int GSIDE, int COST>
__global__ void __launch_bounds__(512, 8) sink_kernel(
    const ushort_t* __restrict__ Lpred, const ushort_t* __restrict__ Rpred,
    const ushort_t* __restrict__ Lgt,   const ushort_t* __restrict__ Rgt,
    float* __restrict__ FT, float* __restrict__ GT,
    float* __restrict__ chamf, float* __restrict__ emd)
{
  // XCD-aware swizzle: give each XCD a contiguous logical range (1024%8==0)
  const int bx0 = blockIdx.x;
  const int bx  = (bx0 & 7) * (NMAT * 32 / 8) + (bx0 >> 3);
  const int m   = bx >> 5;
  const int rg5 = bx & 31;
  const int b   = m >> 1;
  const int tid = threadIdx.x;
  const int l   = tid & 63;
  const int w   = __builtin_amdgcn_readfirstlane(tid >> 6);
  const int wr  = w & 3;
  const int half= w >> 2;

  const ushort_t* A  = GSIDE ? (Lgt + b*65536)   : (Lpred + m*65536);
  const ushort_t* Bm = GSIDE ? (Rpred + m*65536) : (Rgt + b*65536);
  const float* pinT  = (GSIDE ? FT : GT) + m*NPTS;
  float*       poutT = (GSIDE ? GT : FT) + m*NPTS;

  const int rowbase = rg5 * 64;
  const int myrow16 = rowbase + wr * 16;

  __shared__ float ssum[8][16];
  __shared__ float sdm[8][16];   // chamfer mins OR cost T sums (never both)
  __shared__ float sds[4];

  const bf16x8 af = *reinterpret_cast<const bf16x8*>(A + (myrow16 >> 4) * 512 + l * 8);

  float s0=0.f,s1=0.f,s2=0.f,s3=0.f;
  float d0=1e30f,d1=1e30f,d2=1e30f,d3=1e30f;
  float t0=0.f,t1=0.f,t2=0.f,t3=0.f;
  const f32x4 zz = {0.f,0.f,0.f,0.f};
  // wave-uniform base (SGPR) + lane offset (VGPR) + immediate tile offsets
  const ushort_t* Bu = Bm + half * (64*512);
  const int voff = l * 8;
  const float* PTu = pinT + (half*16)*64 + (l & 15)*4;

  auto tilef = [&](const bf16x8& bfr, float pv) {
    f32x4 d4 = __builtin_amdgcn_mfma_f32_16x16x32_bf16(af, bfr, zz, 0, 0, 0);
    const float da=fmaxf(d4[0],1e-12f), db=fmaxf(d4[1],1e-12f);
    const float dc=fmaxf(d4[2],1e-12f), dd=fmaxf(d4[3],1e-12f);
    if (CHAM){ d0=fminf(d0,da); d1=fminf(d1,db); d2=fminf(d2,dc); d3=fminf(d3,dd); }
    const float Ca=fsqrt_(da), Cb=fsqrt_(db), Cc=fsqrt_(dc), Cd=fsqrt_(dd);
    float ea,eb,ec,ed;
    if (RPOT){
      ea=fmaf(-KSCALE,Ca,pv); eb=fmaf(-KSCALE,Cb,pv);
      ec=fmaf(-KSCALE,Cc,pv); ed=fmaf(-KSCALE,Cd,pv);
    } else {
      ea=-KSCALE*Ca; eb=-KSCALE*Cb; ec=-KSCALE*Cc; ed=-KSCALE*Cd;
    }
    const float xa=fexp2(ea), xb=fexp2(eb), xc=fexp2(ec), xd=fexp2(ed);
    s0+=xa; s1+=xb; s2+=xc; s3+=xd;
    if (COST){
      t0=fmaf(xa,Ca,t0); t1=fmaf(xb,Cb,t1);
      t2=fmaf(xc,Cc,t2); t3=fmaf(xd,Cd,t3);
    }
  };

#pragma unroll 2
  for (int g4 = 0; g4 < 16; ++g4) {
    const ushort_t* Bg = Bu + g4 * (4*512);       // uniform (SALU) increment
    float4 cp;
    if (RPOT) cp = *reinterpret_cast<const float4*>(PTu + g4*64);
    else      cp = make_float4(0.f,0.f,0.f,0.f);
    tilef(*reinterpret_cast<const bf16x8*>(Bg + voff + 0*512), cp.x);
    tilef(*reinterpret_cast<const bf16x8*>(Bg + voff + 1*512), cp.y);
    tilef(*reinterpret_cast<const bf16x8*>(Bg + voff + 2*512), cp.z);
    tilef(*reinterpret_cast<const bf16x8*>(Bg + voff + 3*512), cp.w);
  }

  // reduce across the 16 col-lanes of each row
#pragma unroll
  for (int o = 1; o < 16; o <<= 1) {
    s0 += __shfl_xor(s0,o); s1 += __shfl_xor(s1,o);
    s2 += __shfl_xor(s2,o); s3 += __shfl_xor(s3,o);
    if (CHAM){
      d0=fminf(d0,__shfl_xor(d0,o)); d1=fminf(d1,__shfl_xor(d1,o));
      d2=fminf(d2,__shfl_xor(d2,o)); d3=fminf(d3,__shfl_xor(d3,o));
    }
    if (COST){
      t0 += __shfl_xor(t0,o); t1 += __shfl_xor(t1,o);
      t2 += __shfl_xor(t2,o); t3 += __shfl_xor(t3,o);
    }
  }
  if ((l & 15) == 0) {
    const int g = l >> 4;
    ssum[w][g*4+0]=s0; ssum[w][g*4+1]=s1; ssum[w][g*4+2]=s2; ssum[w][g*4+3]=s3;
    if (CHAM){ sdm[w][g*4+0]=d0; sdm[w][g*4+1]=d1; sdm[w][g*4+2]=d2; sdm[w][g*4+3]=d3; }
    if (COST){ sdm[w][g*4+0]=t0; sdm[w][g*4+1]=t1; sdm[w][g*4+2]=t2; sdm[w][g*4+3]=t3; }
  }
  __syncthreads();
  float val = 0.f;
  if (w < 4 && l < 16) {
    const float S = ssum[w][l] + ssum[w+4][l];
    val = -11.0f - flog2(S);
    // row index grow = rg5*64 + w*16 + l -> t4 = rg5, k = w, c = l
    poutT[rg5*64 + l*4 + w] = val;   // dense 256B per block
  }
  if (CHAM) {
    if (w < 4) {
      float dmr = (l < 16) ? fminf(sdm[w][l], sdm[w+4][l]) : 0.f;
#pragma unroll
      for (int o = 1; o < 16; o <<= 1) dmr += __shfl_xor(dmr, o);
      if (l == 0) sds[w] = dmr;
    }
    __syncthreads();
    if (tid == 0) atomicAdd(chamf, (sds[0]+sds[1])+(sds[2]+sds[3]));
  }
  if (COST) {
    if (w < 4) {
      float cj = (l < 16) ? fexp2(val) * (sdm[w][l] + sdm[w+4][l]) : 0.f;
#pragma unroll
      for (int o = 1; o < 16; o <<= 1) cj += __shfl_xor(cj, o);
      if (l == 0) sds[w] = cj;
    }
    __syncthreads();
    if (tid == 0) atomicAdd(emd, (sds[0]+sds[1])+(sds[2]+sds[3]));
  }
}

__global__ void final_kernel(const float* __restrict__ emd,
                             const float* __restrict__ chamf,
                             float* __restrict__ out)
{
  if (blockIdx.x == 0 && threadIdx.x == 0) {
    out[0] = chamf[0] / (float)(BATCH * NPTS) + emd[0] / (float)BATCH;
  }
}

extern "C" void kernel_launch(void* const* d_in, const int* in_sizes, int n_in,
                              void* d_out, int out_size, void* d_ws, size_t ws_size,
                              hipStream_t stream) {
  (void)in_sizes; (void)n_in; (void)out_size; (void)ws_size;
  const float* gt = (const float*)d_in[0];
  const float* p0 = (const float*)d_in[2];
  const float* p1 = (const float*)d_in[3];

  ushort_t* Lpred = (ushort_t*)d_ws;                  // 4MB
  ushort_t* Rpred = Lpred + NMAT * 65536;             // 4MB
  ushort_t* Lgt   = Rpred + NMAT * 65536;             // 2MB
  ushort_t* Rgt   = Lgt + BATCH * 65536;              // 2MB
  float* FT    = (float*)(Rgt + BATCH * 65536);       // 32*2048 (grouped-T)
  float* GT    = FT + NMAT * NPTS;                    // 32*2048 (grouped-T)
  float* emd   = GT + NMAT * NPTS;                    // 1
  float* chamf = emd + 1;                             // 1

  const int initN = (NMAT + BATCH) * NPTS + 2;
  pack_kernel<<<(initN + 255) / 256, 256, 0, stream>>>(gt, p0, p1, Lpred, Rpred, Lgt, Rgt, emd, chamf);

  const int grid = NMAT * 32;   // 1024 blocks, 8 waves each, 64 rows/block
  sink_kernel<1, 0, 0, 0><<<grid, 512, 0, stream>>>(Lpred, Rpred, Lgt, Rgt, FT, GT, chamf, emd);
  sink_kernel<1, 1, 1, 0><<<grid, 512, 0, stream>>>(Lpred, Rpred, Lgt, Rgt, FT, GT, chamf, emd);
  for (int it = 1; it < ITERS - 1; ++it) {
    sink_kernel<0, 1, 0, 0><<<grid, 512, 0, stream>>>(Lpred, Rpred, Lgt, Rgt, FT, GT, chamf, emd);
    sink_kernel<0, 1, 1, 0><<<grid, 512, 0, stream>>>(Lpred, Rpred, Lgt, Rgt, FT, GT, chamf, emd);
  }
  // final iteration: f-update, then g-update with fused EMD cost
  sink_kernel<0, 1, 0, 0><<<grid, 512, 0, stream>>>(Lpred, Rpred, Lgt, Rgt, FT, GT, chamf, emd);
  sink_kernel<0, 1, 1, 1><<<grid, 512, 0, stream>>>(Lpred, Rpred, Lgt, Rgt, FT, GT, chamf, emd);
  final_kernel<<<1, 64, 0, stream>>>(emd, chamf, (float*)d_out);
}